// Round 15
// baseline (75.546 us; speedup 1.0000x reference)
//
#include <hip/hip_runtime.h>
#include <math.h>

#define EPSF   1e-8f
#define CLAMPF 0.99999f   // 1 - 1e-5 (f32)

typedef __attribute__((ext_vector_type(8))) short bf16x8;
typedef __attribute__((ext_vector_type(4))) float f32x4;
#define MFMA16(a,b,c) __builtin_amdgcn_mfma_f32_16x16x32_bf16(a,b,c,0,0,0)

// hardware packed f32x2 -> bf16x2 (single VALU instr); low half = first arg
__device__ __forceinline__ unsigned cvt_pk_bf16(float lo, float hi) {
  unsigned r;
  asm("v_cvt_pk_bf16_f32 %0, %1, %2" : "=v"(r) : "v"(lo), "v"(hi));
  return r;
}

// async global->LDS DMA, 16B/lane, wave-uniform LDS base + lane*16 dest
typedef __attribute__((address_space(1))) const void GV;
typedef __attribute__((address_space(3))) void LV;
__device__ __forceinline__ void gload_lds16(const void* g, void* l) {
  __builtin_amdgcn_global_load_lds((GV*)g, (LV*)l, 16, 0, 0);
}

__device__ __forceinline__ float wave_sum64(float v) {
  v += __shfl_xor(v, 1, 64);
  v += __shfl_xor(v, 2, 64);
  v += __shfl_xor(v, 4, 64);
  v += __shfl_xor(v, 8, 64);
  v += __shfl_xor(v, 16, 64);
  v += __shfl_xor(v, 32, 64);
  return v;
}

// ---------------- fused prep: logmap 2 rows/block (id<2048) + weight bf16 (2048..2559) + bias_ball (2560..2561) ----------------
__global__ __launch_bounds__(256) void prep_logmap(const float* __restrict__ x,
                                                   const float* __restrict__ Wq,
                                                   const float* __restrict__ Wk,
                                                   const float* __restrict__ Wv,
                                                   const float* __restrict__ Wo,
                                                   const float* __restrict__ bq,
                                                   const float* __restrict__ bk,
                                                   short* __restrict__ xe,
                                                   short* __restrict__ Wqbf,
                                                   short* __restrict__ Wkbf,
                                                   short* __restrict__ Wvbf,
                                                   short* __restrict__ Wobf,
                                                   float* __restrict__ bb) {
  const int id = blockIdx.x;
  const int t = threadIdx.x;
  __shared__ float red[4];
  if (id < 2048) {
    const int half = t >> 7, tc = t & 127;
    const int row = id * 2 + half;
    float4 v = ((const float4*)(x + (size_t)row * 512))[tc];
    float s = wave_sum64(v.x * v.x + v.y * v.y + v.z * v.z + v.w * v.w);
    if ((t & 63) == 0) red[t >> 6] = s;
    __syncthreads();
    float n2 = red[half * 2] + red[half * 2 + 1];
    float n = sqrtf(n2);
    float nm = fmaxf(n, EPSF);
    float a = fminf(nm, 1.0f);
    float at = 0.5f * logf((1.f + a) / (1.f - a));
    float sc = at / nm;
    uint2 o;
    o.x = cvt_pk_bf16(v.x * sc, v.y * sc);
    o.y = cvt_pk_bf16(v.z * sc, v.w * sc);
    ((uint2*)(xe + (size_t)row * 512))[tc] = o;
    return;
  }
  const int wid = id - 2048;
  if (wid < 512) {
    const int which = wid >> 7, chunk = wid & 127;
    const float* src; short* dst;
    switch (which) {
      case 0: src = Wq; dst = Wqbf; break;
      case 1: src = Wk; dst = Wkbf; break;
      case 2: src = Wv; dst = Wvbf; break;
      default: src = Wo; dst = Wobf; break;
    }
    const int idx = chunk * 2048 + t * 8;
    float4 a = *(const float4*)(src + idx);
    float4 b2 = *(const float4*)(src + idx + 4);
    union { int4 v; unsigned u[4]; } o;
    o.u[0] = cvt_pk_bf16(a.x, a.y);
    o.u[1] = cvt_pk_bf16(a.z, a.w);
    o.u[2] = cvt_pk_bf16(b2.x, b2.y);
    o.u[3] = cvt_pk_bf16(b2.z, b2.w);
    *(int4*)(dst + idx) = o.v;
    return;
  }
  // bias_ball = expmap0(b); 520 floats each
  const int which = wid - 512;
  const float* b = which ? bk : bq;
  float* o = bb + (size_t)which * 520;
  float2 v = ((const float2*)b)[t];
  float s = wave_sum64(v.x * v.x + v.y * v.y);
  if ((t & 63) == 0) red[t >> 6] = s;
  __syncthreads();
  float n2 = red[0] + red[1] + red[2] + red[3];
  float n = sqrtf(n2);
  float nm = fmaxf(n, EPSF);
  float tt = fminf(nm, 15.f);
  float f = tanhf(tt) / nm;
  float on = f * nm;
  if (on > CLAMPF) f *= CLAMPF / on;
  ((float2*)o)[t] = make_float2(f * v.x, f * v.y);
  if (t == 0) o[512] = f * f * n2;
}

// ---------------- bf16 MFMA GEMM core, 64x64 tile, global_load_lds staging (r14 verified) ----------------
template <int VT>
__device__ __forceinline__ void gemm_core(const short* __restrict__ A,
                                          const short* __restrict__ W,
                                          const float* __restrict__ bias,
                                          void* __restrict__ outp,
                                          int bx, int by) {
  __shared__ __align__(16) short As[64][64];
  __shared__ __align__(16) short Ws[64][64];
  const int t = threadIdx.x;
  const int wave = t >> 6, lane = t & 63, lg = lane >> 4, lr = lane & 15;
  const int mh = wave & 1, nh = wave >> 1;
  f32x4 z = {0.f, 0.f, 0.f, 0.f};
  f32x4 acc00 = z, acc01 = z, acc10 = z, acc11 = z;

  const int rsub = lane >> 3;
  const int swz = ((lane & 7) ^ rsub) * 8;      // shorts
  const short* Ag0 = A + (size_t)(by * 64 + wave * 16 + rsub) * 512 + swz;
  const short* Ag1 = Ag0 + 8 * 512;
  const short* Wg0 = W + (size_t)(bx * 64 + wave * 16 + rsub) * 512 + swz;
  const short* Wg1 = Wg0 + 8 * 512;
  short* Al0 = &As[wave * 16][0];
  short* Al1 = &As[wave * 16 + 8][0];
  short* Wl0 = &Ws[wave * 16][0];
  short* Wl1 = &Ws[wave * 16 + 8][0];

  const int ra = mh * 32 + lr;
  const int rb = nh * 32 + lr;
  const int cx = (lr & 7) * 8;

  for (int kt = 0; kt < 512; kt += 64) {
    __syncthreads();
    gload_lds16(Ag0 + kt, Al0);
    gload_lds16(Ag1 + kt, Al1);
    gload_lds16(Wg0 + kt, Wl0);
    gload_lds16(Wg1 + kt, Wl1);
    __syncthreads();
#pragma unroll
    for (int kk = 0; kk < 2; ++kk) {
      const int c = (kk * 32 + lg * 8) ^ cx;
      bf16x8 af0 = *(const bf16x8*)&As[ra][c];
      bf16x8 af1 = *(const bf16x8*)&As[ra + 16][c];
      bf16x8 bf0 = *(const bf16x8*)&Ws[rb][c];
      bf16x8 bf1 = *(const bf16x8*)&Ws[rb + 16][c];
      acc00 = MFMA16(af0, bf0, acc00);
      acc01 = MFMA16(af0, bf1, acc01);
      acc10 = MFMA16(af1, bf0, acc10);
      acc11 = MFMA16(af1, bf1, acc11);
    }
  }

  if (VT == 0) {
    float* out = (float*)outp;
    float b0 = 0.f, b1 = 0.f;
    if (bias) { b0 = bias[bx * 64 + nh * 32 + lr]; b1 = bias[bx * 64 + nh * 32 + 16 + lr]; }
#pragma unroll
    for (int r = 0; r < 4; ++r) {
      size_t row0 = (size_t)(by * 64 + mh * 32 + lg * 4 + r);
      size_t row1 = row0 + 16;
      out[row0 * 512 + bx * 64 + nh * 32 + lr] = acc00[r] + b0;
      out[row0 * 512 + bx * 64 + nh * 32 + 16 + lr] = acc01[r] + b1;
      out[row1 * 512 + bx * 64 + nh * 32 + lr] = acc10[r] + b0;
      out[row1 * 512 + bx * 64 + nh * 32 + 16 + lr] = acc11[r] + b1;
    }
  } else {
    short* vt = (short*)outp;
    const int bidx = by >> 4;
    const int trow0 = (by & 15) * 64 + mh * 32 + lg * 4;
    const int c0 = bx * 64 + nh * 32 + lr;
    const int c1 = c0 + 16;
    const float b0 = bias[c0], b1 = bias[c1];
    size_t base0 = ((size_t)(bidx * 8 + (c0 >> 6)) * 64 + (c0 & 63)) * 1024;
    size_t base1 = ((size_t)(bidx * 8 + (c1 >> 6)) * 64 + (c1 & 63)) * 1024;
    uint2 pk;
    pk.x = cvt_pk_bf16(acc00[0] + b0, acc00[1] + b0);
    pk.y = cvt_pk_bf16(acc00[2] + b0, acc00[3] + b0);
    *(uint2*)(vt + base0 + trow0) = pk;
    pk.x = cvt_pk_bf16(acc01[0] + b1, acc01[1] + b1);
    pk.y = cvt_pk_bf16(acc01[2] + b1, acc01[3] + b1);
    *(uint2*)(vt + base1 + trow0) = pk;
    pk.x = cvt_pk_bf16(acc10[0] + b0, acc10[1] + b0);
    pk.y = cvt_pk_bf16(acc10[2] + b0, acc10[3] + b0);
    *(uint2*)(vt + base0 + trow0 + 16) = pk;
    pk.x = cvt_pk_bf16(acc11[0] + b1, acc11[1] + b1);
    pk.y = cvt_pk_bf16(acc11[2] + b1, acc11[3] + b1);
    *(uint2*)(vt + base1 + trow0 + 16) = pk;
  }
}

__global__ __launch_bounds__(256) void gemm_qkv(const short* __restrict__ A,
                                                const short* __restrict__ Wq,
                                                const short* __restrict__ Wk,
                                                const short* __restrict__ Wv,
                                                const float* __restrict__ bv,
                                                float* __restrict__ Qo,
                                                float* __restrict__ Ko,
                                                short* __restrict__ Vt) {
  switch (blockIdx.z) {
    case 0: gemm_core<0>(A, Wq, nullptr, Qo, blockIdx.x, blockIdx.y); break;
    case 1: gemm_core<0>(A, Wk, nullptr, Ko, blockIdx.x, blockIdx.y); break;
    default: gemm_core<1>(A, Wv, bv, Vt, blockIdx.x, blockIdx.y); break;
  }
}

__global__ __launch_bounds__(256) void gemm_bf(const short* __restrict__ A,
                                               const short* __restrict__ W,
                                               const float* __restrict__ bias,
                                               float* __restrict__ out) {
  gemm_core<0>(A, W, bias, out, blockIdx.x, blockIdx.y);
}

// ---------------- hyperbolic epilogue v4: 2 rows/block, float4 (r13 verified) ----------------
__global__ __launch_bounds__(256) void hyp_epilogue_v4(const float* __restrict__ Qb,
                                                       const float* __restrict__ Kb,
                                                       const float* __restrict__ bbase,
                                                       short* __restrict__ Qbf,
                                                       short* __restrict__ Kbf,
                                                       float* __restrict__ q2h,
                                                       float* __restrict__ k2h) {
  const int which = blockIdx.y;
  const float* Y = which ? Kb : Qb;
  const float* bb = bbase + (size_t)which * 520;
  short* Ybf = which ? Kbf : Qbf;
  float* y2h = which ? k2h : q2h;
  const int t = threadIdx.x;
  const int half = t >> 7, tc = t & 127;
  const int row = blockIdx.x * 2 + half;

  float4 y = ((const float4*)(Y + (size_t)row * 512))[tc];
  float4 w = ((const float4*)bb)[tc];
  __shared__ float red[8];
  float sn = wave_sum64(y.x * y.x + y.y * y.y + y.z * y.z + y.w * y.w);
  float sd = wave_sum64(y.x * w.x + y.y * w.y + y.z * w.z + y.w * w.w);
  if ((t & 63) == 0) { red[t >> 6] = sn; red[4 + (t >> 6)] = sd; }
  __syncthreads();
  float n2 = red[half * 2] + red[half * 2 + 1];
  float dt = red[4 + half * 2] + red[4 + half * 2 + 1];
  float y2 = bb[512];
  float n = sqrtf(n2);
  float nm = fmaxf(n, EPSF);
  float tt = fminf(nm, 15.f);
  float f = tanhf(tt) / nm;
  float on = f * nm;
  if (on > CLAMPF) f *= CLAMPF / on;
  float x2 = f * f * n2;
  float xy = f * dt;
  float A = 1.f + 2.f * xy + y2;
  float Bc = 1.f - x2;
  float den = fmaxf(1.f + 2.f * xy + x2 * y2, EPSF);
  float num2 = A * A * x2 + Bc * Bc * y2 + 2.f * A * Bc * xy;
  float nn = sqrtf(fmaxf(num2, 0.f)) / den;
  float nnm = fmaxf(nn, EPSF);
  float s2 = (nnm > CLAMPF) ? (CLAMPF / nnm) : 1.f;
  float g = s2 / den;
  float ox = g * (A * f * y.x + Bc * w.x);
  float oy = g * (A * f * y.y + Bc * w.y);
  float oz = g * (A * f * y.z + Bc * w.z);
  float ow = g * (A * f * y.w + Bc * w.w);
  uint2 o;
  o.x = cvt_pk_bf16(ox, oy);
  o.y = cvt_pk_bf16(oz, ow);
  ((uint2*)(Ybf + (size_t)row * 512))[tc] = o;
  float hs = ox * ox + oy * oy + oz * oz + ow * ow;
  hs += __shfl_xor(hs, 1, 64);
  hs += __shfl_xor(hs, 2, 64);
  hs += __shfl_xor(hs, 4, 64);
  hs += __shfl_xor(hs, 8, 64);
  if ((tc & 15) == 0) y2h[(size_t)(tc >> 4) * 4096 + row] = hs;
}

// ---------------- MFMA flash attention v7: BK=128 (two 64-key sub-tiles per staging round) ----------------
// Grid 512, block 512 = 8 waves (qh = wave>>1, kh = wave&1). 8 iterations x 128 keys.
// Per-sub-tile inner body byte-identical to r10/r12-verified mapping (kwr-permuted K,
// register-resident P, natural Vs columns). Barriers: 16 total (was 32).
__global__ __launch_bounds__(512, 2) void attn_mfma_v7(const short* __restrict__ Qbf,
                                                       const short* __restrict__ Kbf,
                                                       const float* __restrict__ q2h,
                                                       const float* __restrict__ k2h,
                                                       const short* __restrict__ Vt,
                                                       short* __restrict__ Obf) {
  __shared__ __align__(16) short Ks[2][64][72];
  __shared__ __align__(16) short Vs[2][64][72];
  __shared__ __align__(16) float k2s[128];
  __shared__ __align__(16) float Ls[4][16][68];
  __shared__ float lsb[4][16];

  const int t = threadIdx.x;
  const int id = blockIdx.x;               // id = qt*32 + b*8 + hd
  const int qt = id >> 5;                  // 0..15 (64-query tiles)
  const int pr = (((id >> 3) & 3) << 3) | (id & 7);
  const int hd = pr & 7, b = pr >> 3;
  const int wave = t >> 6, lane = t & 63, lg = lane >> 4, lr = lane & 15;
  const int qh = wave >> 1, kh = wave & 1;

  const size_t qrow = (size_t)(b * 1024 + qt * 64 + qh * 16 + lr);
  const bf16x8 qf0 = *(const bf16x8*)(Qbf + qrow * 512 + hd * 64 + lg * 8);
  const bf16x8 qf1 = *(const bf16x8*)(Qbf + qrow * 512 + hd * 64 + 32 + lg * 8);

  const float q2 = q2h[(size_t)hd * 4096 + b * 1024 + qt * 64 + qh * 16 + lr];
  const float bc = 1.f - q2;
  const float bc2 = bc * bc;
  const float q2p1m2 = -2.f * (1.f + q2);

  // staging: thread covers key-row/dv-row sr of BOTH sub-tiles, 16B chunk q8
  const int sr = t >> 3, q8 = t & 7;
  const int p32 = sr & 31;
  const int kwr = (sr & 32) | (((p32 >> 2) & 1) << 4) | (((p32 >> 3) & 3) << 2) | (p32 & 3);
  const short* kgp = Kbf + (size_t)(b * 1024 + sr) * 512 + hd * 64 + q8 * 8;
  const short* vgp = Vt + ((size_t)(b * 8 + hd) * 64 + sr) * 1024 + q8 * 8;
  const float* k2gp = k2h + (size_t)hd * 4096 + b * 1024 + t;

  int4 rk0 = *(const int4*)kgp;
  int4 rk1 = *(const int4*)(kgp + (size_t)64 * 512);
  int4 rv0 = *(const int4*)vgp;
  int4 rv1 = *(const int4*)(vgp + 64);
  float rk2 = (t < 128) ? *k2gp : 0.f;

  f32x4 z = {0.f, 0.f, 0.f, 0.f};
  f32x4 acc0 = z, acc1 = z, acc2 = z, acc3 = z;
  float ls = 0.f;
  const int krow = kh * 32 + lr;
  const int kcol = kh * 32 + lg * 8;

  for (int kt = 0; kt < 8; ++kt) {
    __syncthreads();   // (A) prior pair fully consumed
    *(int4*)&Ks[0][kwr][q8 * 8] = rk0;
    *(int4*)&Ks[1][kwr][q8 * 8] = rk1;
    *(int4*)&Vs[0][sr][q8 * 8] = rv0;
    *(int4*)&Vs[1][sr][q8 * 8] = rv1;
    if (t < 128) k2s[t] = rk2;
    __syncthreads();   // (B) pair staged
    if (kt < 7) {      // prefetch next pair; latency hides under 2 sub-tiles of compute
      kgp += 128 * 512; vgp += 128; k2gp += 128;
      rk0 = *(const int4*)kgp;
      rk1 = *(const int4*)(kgp + (size_t)64 * 512);
      rv0 = *(const int4*)vgp;
      rv1 = *(const int4*)(vgp + 64);
      if (t < 128) rk2 = *k2gp;
    }

#pragma unroll
    for (int s = 0; s < 2; ++s) {
      // QK^T (swapped): subtile A rows = keys lg*8+r; subtile B (+16) = keys lg*8+4+r
      bf16x8 kf0 = *(const bf16x8*)&Ks[s][krow][lg * 8];
      bf16x8 kf1 = *(const bf16x8*)&Ks[s][krow][32 + lg * 8];
      bf16x8 kg0 = *(const bf16x8*)&Ks[s][krow + 16][lg * 8];
      bf16x8 kg1 = *(const bf16x8*)&Ks[s][krow + 16][32 + lg * 8];
      f32x4 sA = MFMA16(kf0, qf0, z);
      sA = MFMA16(kf1, qf1, sA);
      f32x4 sB = MFMA16(kg0, qf0, z);
      sB = MFMA16(kg1, qf1, sB);

      float pA[4], pB[4];
#pragma unroll
      for (int r = 0; r < 4; ++r) {
        float d = sA[r];
        float k2v = k2s[s * 64 + kh * 32 + lg * 8 + r];
        float k2p1 = 1.f + k2v;
        float c1 = q2p1m2 * k2p1;
        float c0 = fmaf(q2, k2p1 * k2p1, bc2 * k2v);
        float num2 = fmaxf(fmaf(d, fmaf(4.f, d, c1), c0), 0.f);
        float den = fmaxf(fmaf(-2.f, d, fmaf(q2, k2v, 1.f)), EPSF);
        float sq = __builtin_amdgcn_sqrtf(num2);
        float u = fmaxf((den - sq) * __builtin_amdgcn_rcpf(den + sq), 5.000025e-6f);
        pA[r] = __builtin_amdgcn_exp2f(0.125f * __builtin_amdgcn_logf(u));
      }
#pragma unroll
      for (int r = 0; r < 4; ++r) {
        float d = sB[r];
        float k2v = k2s[s * 64 + kh * 32 + lg * 8 + 4 + r];
        float k2p1 = 1.f + k2v;
        float c1 = q2p1m2 * k2p1;
        float c0 = fmaf(q2, k2p1 * k2p1, bc2 * k2v);
        float num2 = fmaxf(fmaf(d, fmaf(4.f, d, c1), c0), 0.f);
        float den = fmaxf(fmaf(-2.f, d, fmaf(q2, k2v, 1.f)), EPSF);
        float sq = __builtin_amdgcn_sqrtf(num2);
        float u = fmaxf((den - sq) * __builtin_amdgcn_rcpf(den + sq), 5.000025e-6f);
        pB[r] = __builtin_amdgcn_exp2f(0.125f * __builtin_amdgcn_logf(u));
      }
      ls += (pA[0] + pA[1] + pA[2] + pA[3]) + (pB[0] + pB[1] + pB[2] + pB[3]);

      union { unsigned u[4]; bf16x8 v; } pf;
      pf.u[0] = cvt_pk_bf16(pA[0], pA[1]);
      pf.u[1] = cvt_pk_bf16(pA[2], pA[3]);
      pf.u[2] = cvt_pk_bf16(pB[0], pB[1]);
      pf.u[3] = cvt_pk_bf16(pB[2], pB[3]);

      bf16x8 v0 = *(const bf16x8*)&Vs[s][lr][kcol];
      bf16x8 v1 = *(const bf16x8*)&Vs[s][16 + lr][kcol];
      bf16x8 v2 = *(const bf16x8*)&Vs[s][32 + lr][kcol];
      bf16x8 v3 = *(const bf16x8*)&Vs[s][48 + lr][kcol];
      acc0 = MFMA16(v0, pf.v, acc0);
      acc1 = MFMA16(v1, pf.v, acc1);
      acc2 = MFMA16(v2, pf.v, acc2);
      acc3 = MFMA16(v3, pf.v, acc3);
    }
  }

  // reduce ls over the 4 lg key-groups (same q = lr, same kh)
  ls += __shfl_xor(ls, 16, 64);
  ls += __shfl_xor(ls, 32, 64);

  // cross-kh combine via dedicated arrays
  if (kh == 1) {
    float* Lq = &Ls[qh][lr][0];
    *(f32x4*)(Lq + lg * 4) = acc0;
    *(f32x4*)(Lq + 16 + lg * 4) = acc1;
    *(f32x4*)(Lq + 32 + lg * 4) = acc2;
    *(f32x4*)(Lq + 48 + lg * 4) = acc3;
    if (lg == 0) lsb[qh][lr] = ls;
  }
  __syncthreads();
  if (kh == 0) {
    const float* Lq = &Ls[qh][lr][0];
    acc0 += *(const f32x4*)(Lq + lg * 4);
    acc1 += *(const f32x4*)(Lq + 16 + lg * 4);
    acc2 += *(const f32x4*)(Lq + 32 + lg * 4);
    acc3 += *(const f32x4*)(Lq + 48 + lg * 4);
    float inv = 1.f / (ls + lsb[qh][lr]);
    short* ob = Obf + qrow * 512 + hd * 64 + lg * 4;
    uint2 pk;
    pk.x = cvt_pk_bf16(acc0[0] * inv, acc0[1] * inv);
    pk.y = cvt_pk_bf16(acc0[2] * inv, acc0[3] * inv);
    *(uint2*)(ob) = pk;
    pk.x = cvt_pk_bf16(acc1[0] * inv, acc1[1] * inv);
    pk.y = cvt_pk_bf16(acc1[2] * inv, acc1[3] * inv);
    *(uint2*)(ob + 16) = pk;
    pk.x = cvt_pk_bf16(acc2[0] * inv, acc2[1] * inv);
    pk.y = cvt_pk_bf16(acc2[2] * inv, acc2[3] * inv);
    *(uint2*)(ob + 32) = pk;
    pk.x = cvt_pk_bf16(acc3[0] * inv, acc3[1] * inv);
    pk.y = cvt_pk_bf16(acc3[2] * inv, acc3[3] * inv);
    *(uint2*)(ob + 48) = pk;
  }
}

// ---------------- launch ----------------
extern "C" void kernel_launch(void* const* d_in, const int* in_sizes, int n_in,
                              void* d_out, int out_size, void* d_ws, size_t ws_size,
                              hipStream_t stream) {
  const float* x  = (const float*)d_in[0];
  const float* Wq = (const float*)d_in[1];
  const float* bq = (const float*)d_in[2];
  const float* Wk = (const float*)d_in[3];
  const float* bk = (const float*)d_in[4];
  const float* Wv = (const float*)d_in[5];
  const float* bv = (const float*)d_in[6];
  const float* Wo = (const float*)d_in[7];
  const float* bo = (const float*)d_in[8];
  float* out = (float*)d_out;
  float* ws  = (float*)d_ws;

  const size_t M1 = 1048576ull;  // 1M floats
  // ws layout (float units); [4096][512] bf16 = 2M shorts = 1M floats:
  //   Qb [0,2M) fp32 | Kb [2M,4M) fp32 | Vt [4M,5M) bf16 | xe/Qbf [5M,6M) bf16
  //   W*bf [6M,6.5M) | attn_out [6.5M,7.5M) bf16
  // d_out scratch (consumed before final GEMM): Kbf [0,1M) | bb | q2h | k2h
  float* Qb    = ws;
  float* Kb    = ws + 2 * M1;
  short* Vt    = (short*)(ws + 4 * M1);
  short* xe_bf = (short*)(ws + 5 * M1);
  short* Qbf   = (short*)(ws + 5 * M1);      // reuse xe after gemm_qkv
  short* Wqbf  = (short*)(ws + 6 * M1);
  short* Wkbf  = (short*)(ws + 6 * M1 + 131072);
  short* Wvbf  = (short*)(ws + 6 * M1 + 262144);
  short* Wobf  = (short*)(ws + 6 * M1 + 393216);
  short* attn_out = (short*)(ws + 6 * M1 + 524288);
  short* Kbf = (short*)out;
  float* bb  = out + M1;
  float* q2h = out + M1 + 2048;
  float* k2h = out + M1 + 2048 + 32768;

  hipLaunchKernelGGL(prep_logmap, dim3(2562), dim3(256), 0, stream,
                     x, Wq, Wk, Wv, Wo, bq, bk, xe_bf, Wqbf, Wkbf, Wvbf, Wobf, bb);

  hipLaunchKernelGGL(gemm_qkv, dim3(8, 64, 3), dim3(256), 0, stream,
                     xe_bf, Wqbf, Wkbf, Wvbf, bv, Qb, Kb, Vt);

  hipLaunchKernelGGL(hyp_epilogue_v4, dim3(2048, 2), dim3(256), 0, stream,
                     Qb, Kb, bb, Qbf, Kbf, q2h, k2h);

  hipLaunchKernelGGL(attn_mfma_v7, dim3(512), dim3(512), 0, stream,
                     Qbf, Kbf, q2h, k2h, Vt, attn_out);

  hipLaunchKernelGGL(gemm_bf, dim3(8, 64), dim3(256), 0, stream, attn_out, Wobf, bo, out);
}

// Round 16
// 74.619 us; speedup vs baseline: 1.0124x; 1.0124x over previous
//
#include <hip/hip_runtime.h>
#include <math.h>

#define EPSF   1e-8f
#define CLAMPF 0.99999f   // 1 - 1e-5 (f32)

typedef __attribute__((ext_vector_type(8))) short bf16x8;
typedef __attribute__((ext_vector_type(4))) float f32x4;
#define MFMA16(a,b,c) __builtin_amdgcn_mfma_f32_16x16x32_bf16(a,b,c,0,0,0)

// hardware packed f32x2 -> bf16x2 (single VALU instr); low half = first arg
__device__ __forceinline__ unsigned cvt_pk_bf16(float lo, float hi) {
  unsigned r;
  asm("v_cvt_pk_bf16_f32 %0, %1, %2" : "=v"(r) : "v"(lo), "v"(hi));
  return r;
}

// async global->LDS DMA, 16B/lane, wave-uniform LDS base + lane*16 dest
typedef __attribute__((address_space(1))) const void GV;
typedef __attribute__((address_space(3))) void LV;
__device__ __forceinline__ void gload_lds16(const void* g, void* l) {
  __builtin_amdgcn_global_load_lds((GV*)g, (LV*)l, 16, 0, 0);
}

__device__ __forceinline__ float wave_sum64(float v) {
  v += __shfl_xor(v, 1, 64);
  v += __shfl_xor(v, 2, 64);
  v += __shfl_xor(v, 4, 64);
  v += __shfl_xor(v, 8, 64);
  v += __shfl_xor(v, 16, 64);
  v += __shfl_xor(v, 32, 64);
  return v;
}

// ---------------- fused prep: logmap 2 rows/block (id<2048) + weight bf16 (2048..2559) + bias_ball (2560..2561) ----------------
__global__ __launch_bounds__(256) void prep_logmap(const float* __restrict__ x,
                                                   const float* __restrict__ Wq,
                                                   const float* __restrict__ Wk,
                                                   const float* __restrict__ Wv,
                                                   const float* __restrict__ Wo,
                                                   const float* __restrict__ bq,
                                                   const float* __restrict__ bk,
                                                   short* __restrict__ xe,
                                                   short* __restrict__ Wqbf,
                                                   short* __restrict__ Wkbf,
                                                   short* __restrict__ Wvbf,
                                                   short* __restrict__ Wobf,
                                                   float* __restrict__ bb) {
  const int id = blockIdx.x;
  const int t = threadIdx.x;
  __shared__ float red[4];
  if (id < 2048) {
    const int half = t >> 7, tc = t & 127;
    const int row = id * 2 + half;
    float4 v = ((const float4*)(x + (size_t)row * 512))[tc];
    float s = wave_sum64(v.x * v.x + v.y * v.y + v.z * v.z + v.w * v.w);
    if ((t & 63) == 0) red[t >> 6] = s;
    __syncthreads();
    float n2 = red[half * 2] + red[half * 2 + 1];
    float n = sqrtf(n2);
    float nm = fmaxf(n, EPSF);
    float a = fminf(nm, 1.0f);
    float at = 0.5f * logf((1.f + a) / (1.f - a));
    float sc = at / nm;
    uint2 o;
    o.x = cvt_pk_bf16(v.x * sc, v.y * sc);
    o.y = cvt_pk_bf16(v.z * sc, v.w * sc);
    ((uint2*)(xe + (size_t)row * 512))[tc] = o;
    return;
  }
  const int wid = id - 2048;
  if (wid < 512) {
    const int which = wid >> 7, chunk = wid & 127;
    const float* src; short* dst;
    switch (which) {
      case 0: src = Wq; dst = Wqbf; break;
      case 1: src = Wk; dst = Wkbf; break;
      case 2: src = Wv; dst = Wvbf; break;
      default: src = Wo; dst = Wobf; break;
    }
    const int idx = chunk * 2048 + t * 8;
    float4 a = *(const float4*)(src + idx);
    float4 b2 = *(const float4*)(src + idx + 4);
    union { int4 v; unsigned u[4]; } o;
    o.u[0] = cvt_pk_bf16(a.x, a.y);
    o.u[1] = cvt_pk_bf16(a.z, a.w);
    o.u[2] = cvt_pk_bf16(b2.x, b2.y);
    o.u[3] = cvt_pk_bf16(b2.z, b2.w);
    *(int4*)(dst + idx) = o.v;
    return;
  }
  // bias_ball = expmap0(b); 520 floats each
  const int which = wid - 512;
  const float* b = which ? bk : bq;
  float* o = bb + (size_t)which * 520;
  float2 v = ((const float2*)b)[t];
  float s = wave_sum64(v.x * v.x + v.y * v.y);
  if ((t & 63) == 0) red[t >> 6] = s;
  __syncthreads();
  float n2 = red[0] + red[1] + red[2] + red[3];
  float n = sqrtf(n2);
  float nm = fmaxf(n, EPSF);
  float tt = fminf(nm, 15.f);
  float f = tanhf(tt) / nm;
  float on = f * nm;
  if (on > CLAMPF) f *= CLAMPF / on;
  ((float2*)o)[t] = make_float2(f * v.x, f * v.y);
  if (t == 0) o[512] = f * f * n2;
}

// ---------------- bf16 MFMA GEMM core, 64x64 tile, global_load_lds staging (r14 verified) ----------------
template <int VT>
__device__ __forceinline__ void gemm_core(const short* __restrict__ A,
                                          const short* __restrict__ W,
                                          const float* __restrict__ bias,
                                          void* __restrict__ outp,
                                          int bx, int by) {
  __shared__ __align__(16) short As[64][64];
  __shared__ __align__(16) short Ws[64][64];
  const int t = threadIdx.x;
  const int wave = t >> 6, lane = t & 63, lg = lane >> 4, lr = lane & 15;
  const int mh = wave & 1, nh = wave >> 1;
  f32x4 z = {0.f, 0.f, 0.f, 0.f};
  f32x4 acc00 = z, acc01 = z, acc10 = z, acc11 = z;

  const int rsub = lane >> 3;
  const int swz = ((lane & 7) ^ rsub) * 8;      // shorts
  const short* Ag0 = A + (size_t)(by * 64 + wave * 16 + rsub) * 512 + swz;
  const short* Ag1 = Ag0 + 8 * 512;
  const short* Wg0 = W + (size_t)(bx * 64 + wave * 16 + rsub) * 512 + swz;
  const short* Wg1 = Wg0 + 8 * 512;
  short* Al0 = &As[wave * 16][0];
  short* Al1 = &As[wave * 16 + 8][0];
  short* Wl0 = &Ws[wave * 16][0];
  short* Wl1 = &Ws[wave * 16 + 8][0];

  const int ra = mh * 32 + lr;
  const int rb = nh * 32 + lr;
  const int cx = (lr & 7) * 8;

  for (int kt = 0; kt < 512; kt += 64) {
    __syncthreads();
    gload_lds16(Ag0 + kt, Al0);
    gload_lds16(Ag1 + kt, Al1);
    gload_lds16(Wg0 + kt, Wl0);
    gload_lds16(Wg1 + kt, Wl1);
    __syncthreads();
#pragma unroll
    for (int kk = 0; kk < 2; ++kk) {
      const int c = (kk * 32 + lg * 8) ^ cx;
      bf16x8 af0 = *(const bf16x8*)&As[ra][c];
      bf16x8 af1 = *(const bf16x8*)&As[ra + 16][c];
      bf16x8 bf0 = *(const bf16x8*)&Ws[rb][c];
      bf16x8 bf1 = *(const bf16x8*)&Ws[rb + 16][c];
      acc00 = MFMA16(af0, bf0, acc00);
      acc01 = MFMA16(af0, bf1, acc01);
      acc10 = MFMA16(af1, bf0, acc10);
      acc11 = MFMA16(af1, bf1, acc11);
    }
  }

  if (VT == 0) {
    float* out = (float*)outp;
    float b0 = 0.f, b1 = 0.f;
    if (bias) { b0 = bias[bx * 64 + nh * 32 + lr]; b1 = bias[bx * 64 + nh * 32 + 16 + lr]; }
#pragma unroll
    for (int r = 0; r < 4; ++r) {
      size_t row0 = (size_t)(by * 64 + mh * 32 + lg * 4 + r);
      size_t row1 = row0 + 16;
      out[row0 * 512 + bx * 64 + nh * 32 + lr] = acc00[r] + b0;
      out[row0 * 512 + bx * 64 + nh * 32 + 16 + lr] = acc01[r] + b1;
      out[row1 * 512 + bx * 64 + nh * 32 + lr] = acc10[r] + b0;
      out[row1 * 512 + bx * 64 + nh * 32 + 16 + lr] = acc11[r] + b1;
    }
  } else {
    short* vt = (short*)outp;
    const int bidx = by >> 4;
    const int trow0 = (by & 15) * 64 + mh * 32 + lg * 4;
    const int c0 = bx * 64 + nh * 32 + lr;
    const int c1 = c0 + 16;
    const float b0 = bias[c0], b1 = bias[c1];
    size_t base0 = ((size_t)(bidx * 8 + (c0 >> 6)) * 64 + (c0 & 63)) * 1024;
    size_t base1 = ((size_t)(bidx * 8 + (c1 >> 6)) * 64 + (c1 & 63)) * 1024;
    uint2 pk;
    pk.x = cvt_pk_bf16(acc00[0] + b0, acc00[1] + b0);
    pk.y = cvt_pk_bf16(acc00[2] + b0, acc00[3] + b0);
    *(uint2*)(vt + base0 + trow0) = pk;
    pk.x = cvt_pk_bf16(acc01[0] + b1, acc01[1] + b1);
    pk.y = cvt_pk_bf16(acc01[2] + b1, acc01[3] + b1);
    *(uint2*)(vt + base1 + trow0) = pk;
    pk.x = cvt_pk_bf16(acc10[0] + b0, acc10[1] + b0);
    pk.y = cvt_pk_bf16(acc10[2] + b0, acc10[3] + b0);
    *(uint2*)(vt + base0 + trow0 + 16) = pk;
    pk.x = cvt_pk_bf16(acc11[0] + b1, acc11[1] + b1);
    pk.y = cvt_pk_bf16(acc11[2] + b1, acc11[3] + b1);
    *(uint2*)(vt + base1 + trow0 + 16) = pk;
  }
}

__global__ __launch_bounds__(256) void gemm_qkv(const short* __restrict__ A,
                                                const short* __restrict__ Wq,
                                                const short* __restrict__ Wk,
                                                const short* __restrict__ Wv,
                                                const float* __restrict__ bv,
                                                float* __restrict__ Qo,
                                                float* __restrict__ Ko,
                                                short* __restrict__ Vt) {
  switch (blockIdx.z) {
    case 0: gemm_core<0>(A, Wq, nullptr, Qo, blockIdx.x, blockIdx.y); break;
    case 1: gemm_core<0>(A, Wk, nullptr, Ko, blockIdx.x, blockIdx.y); break;
    default: gemm_core<1>(A, Wv, bv, Vt, blockIdx.x, blockIdx.y); break;
  }
}

__global__ __launch_bounds__(256) void gemm_bf(const short* __restrict__ A,
                                               const short* __restrict__ W,
                                               const float* __restrict__ bias,
                                               float* __restrict__ out) {
  gemm_core<0>(A, W, bias, out, blockIdx.x, blockIdx.y);
}

// ---------------- hyperbolic epilogue v4: 2 rows/block, float4 (r13 verified) ----------------
__global__ __launch_bounds__(256) void hyp_epilogue_v4(const float* __restrict__ Qb,
                                                       const float* __restrict__ Kb,
                                                       const float* __restrict__ bbase,
                                                       short* __restrict__ Qbf,
                                                       short* __restrict__ Kbf,
                                                       float* __restrict__ q2h,
                                                       float* __restrict__ k2h) {
  const int which = blockIdx.y;
  const float* Y = which ? Kb : Qb;
  const float* bb = bbase + (size_t)which * 520;
  short* Ybf = which ? Kbf : Qbf;
  float* y2h = which ? k2h : q2h;
  const int t = threadIdx.x;
  const int half = t >> 7, tc = t & 127;
  const int row = blockIdx.x * 2 + half;

  float4 y = ((const float4*)(Y + (size_t)row * 512))[tc];
  float4 w = ((const float4*)bb)[tc];
  __shared__ float red[8];
  float sn = wave_sum64(y.x * y.x + y.y * y.y + y.z * y.z + y.w * y.w);
  float sd = wave_sum64(y.x * w.x + y.y * w.y + y.z * w.z + y.w * w.w);
  if ((t & 63) == 0) { red[t >> 6] = sn; red[4 + (t >> 6)] = sd; }
  __syncthreads();
  float n2 = red[half * 2] + red[half * 2 + 1];
  float dt = red[4 + half * 2] + red[4 + half * 2 + 1];
  float y2 = bb[512];
  float n = sqrtf(n2);
  float nm = fmaxf(n, EPSF);
  float tt = fminf(nm, 15.f);
  float f = tanhf(tt) / nm;
  float on = f * nm;
  if (on > CLAMPF) f *= CLAMPF / on;
  float x2 = f * f * n2;
  float xy = f * dt;
  float A = 1.f + 2.f * xy + y2;
  float Bc = 1.f - x2;
  float den = fmaxf(1.f + 2.f * xy + x2 * y2, EPSF);
  float num2 = A * A * x2 + Bc * Bc * y2 + 2.f * A * Bc * xy;
  float nn = sqrtf(fmaxf(num2, 0.f)) / den;
  float nnm = fmaxf(nn, EPSF);
  float s2 = (nnm > CLAMPF) ? (CLAMPF / nnm) : 1.f;
  float g = s2 / den;
  float ox = g * (A * f * y.x + Bc * w.x);
  float oy = g * (A * f * y.y + Bc * w.y);
  float oz = g * (A * f * y.z + Bc * w.z);
  float ow = g * (A * f * y.w + Bc * w.w);
  uint2 o;
  o.x = cvt_pk_bf16(ox, oy);
  o.y = cvt_pk_bf16(oz, ow);
  ((uint2*)(Ybf + (size_t)row * 512))[tc] = o;
  float hs = ox * ox + oy * oy + oz * oz + ow * ow;
  hs += __shfl_xor(hs, 1, 64);
  hs += __shfl_xor(hs, 2, 64);
  hs += __shfl_xor(hs, 4, 64);
  hs += __shfl_xor(hs, 8, 64);
  if ((tc & 15) == 0) y2h[(size_t)(tc >> 4) * 4096 + row] = hs;
}

// ---------------- MFMA flash attention v6 + s_setprio around MFMA clusters (T5) ----------------
// Grid 512, block 512 = 8 waves (qh = wave>>1, kh = wave&1). r12-verified structure/numerics.
__global__ __launch_bounds__(512, 2) void attn_mfma_v6(const short* __restrict__ Qbf,
                                                       const short* __restrict__ Kbf,
                                                       const float* __restrict__ q2h,
                                                       const float* __restrict__ k2h,
                                                       const short* __restrict__ Vt,
                                                       short* __restrict__ Obf) {
  __shared__ __align__(16) short Ks[64][72];
  __shared__ __align__(16) short Vs[64][72];
  __shared__ __align__(16) float k2s[64];
  __shared__ __align__(16) float Ls[4][16][68];
  __shared__ float lsb[4][16];

  const int t = threadIdx.x;
  const int id = blockIdx.x;               // id = qt*32 + b*8 + hd
  const int qt = id >> 5;                  // 0..15 (64-query tiles)
  const int pr = (((id >> 3) & 3) << 3) | (id & 7);
  const int hd = pr & 7, b = pr >> 3;
  const int wave = t >> 6, lane = t & 63, lg = lane >> 4, lr = lane & 15;
  const int qh = wave >> 1, kh = wave & 1;

  const size_t qrow = (size_t)(b * 1024 + qt * 64 + qh * 16 + lr);
  const bf16x8 qf0 = *(const bf16x8*)(Qbf + qrow * 512 + hd * 64 + lg * 8);
  const bf16x8 qf1 = *(const bf16x8*)(Qbf + qrow * 512 + hd * 64 + 32 + lg * 8);

  const float q2 = q2h[(size_t)hd * 4096 + b * 1024 + qt * 64 + qh * 16 + lr];
  const float bc = 1.f - q2;
  const float bc2 = bc * bc;
  const float q2p1m2 = -2.f * (1.f + q2);

  const int sr = t >> 3, q8 = t & 7;
  const int p32 = sr & 31;
  const int kwr = (sr & 32) | (((p32 >> 2) & 1) << 4) | (((p32 >> 3) & 3) << 2) | (p32 & 3);
  const short* kgp = Kbf + (size_t)(b * 1024 + sr) * 512 + hd * 64 + q8 * 8;
  const short* vgp = Vt + ((size_t)(b * 8 + hd) * 64 + sr) * 1024 + q8 * 8;
  const float* k2gp = k2h + (size_t)hd * 4096 + b * 1024 + t;

  int4 rk0 = *(const int4*)kgp;
  int4 rv0 = *(const int4*)vgp;
  float rk2 = (t < 64) ? *k2gp : 0.f;

  f32x4 z = {0.f, 0.f, 0.f, 0.f};
  f32x4 acc0 = z, acc1 = z, acc2 = z, acc3 = z;
  float ls = 0.f;
  const int krow = kh * 32 + lr;
  const int kcol = kh * 32 + lg * 8;

  for (int kt = 0; kt < 16; ++kt) {
    __syncthreads();
    *(int4*)&Ks[kwr][q8 * 8] = rk0;
    *(int4*)&Vs[sr][q8 * 8] = rv0;
    if (t < 64) k2s[t] = rk2;
    __syncthreads();
    if (kt < 15) {
      kgp += 64 * 512; vgp += 64; k2gp += 64;
      rk0 = *(const int4*)kgp;
      rv0 = *(const int4*)vgp;
      if (t < 64) rk2 = *k2gp;
    }

    bf16x8 kf0 = *(const bf16x8*)&Ks[krow][lg * 8];
    bf16x8 kf1 = *(const bf16x8*)&Ks[krow][32 + lg * 8];
    bf16x8 kg0 = *(const bf16x8*)&Ks[krow + 16][lg * 8];
    bf16x8 kg1 = *(const bf16x8*)&Ks[krow + 16][32 + lg * 8];
    __builtin_amdgcn_s_setprio(1);
    f32x4 sA = MFMA16(kf0, qf0, z);
    sA = MFMA16(kf1, qf1, sA);
    f32x4 sB = MFMA16(kg0, qf0, z);
    sB = MFMA16(kg1, qf1, sB);
    __builtin_amdgcn_s_setprio(0);

    float pA[4], pB[4];
#pragma unroll
    for (int r = 0; r < 4; ++r) {
      float d = sA[r];
      float k2v = k2s[kh * 32 + lg * 8 + r];
      float k2p1 = 1.f + k2v;
      float c1 = q2p1m2 * k2p1;
      float c0 = fmaf(q2, k2p1 * k2p1, bc2 * k2v);
      float num2 = fmaxf(fmaf(d, fmaf(4.f, d, c1), c0), 0.f);
      float den = fmaxf(fmaf(-2.f, d, fmaf(q2, k2v, 1.f)), EPSF);
      float sq = __builtin_amdgcn_sqrtf(num2);
      float u = fmaxf((den - sq) * __builtin_amdgcn_rcpf(den + sq), 5.000025e-6f);
      pA[r] = __builtin_amdgcn_exp2f(0.125f * __builtin_amdgcn_logf(u));
    }
#pragma unroll
    for (int r = 0; r < 4; ++r) {
      float d = sB[r];
      float k2v = k2s[kh * 32 + lg * 8 + 4 + r];
      float k2p1 = 1.f + k2v;
      float c1 = q2p1m2 * k2p1;
      float c0 = fmaf(q2, k2p1 * k2p1, bc2 * k2v);
      float num2 = fmaxf(fmaf(d, fmaf(4.f, d, c1), c0), 0.f);
      float den = fmaxf(fmaf(-2.f, d, fmaf(q2, k2v, 1.f)), EPSF);
      float sq = __builtin_amdgcn_sqrtf(num2);
      float u = fmaxf((den - sq) * __builtin_amdgcn_rcpf(den + sq), 5.000025e-6f);
      pB[r] = __builtin_amdgcn_exp2f(0.125f * __builtin_amdgcn_logf(u));
    }
    ls += (pA[0] + pA[1] + pA[2] + pA[3]) + (pB[0] + pB[1] + pB[2] + pB[3]);

    union { unsigned u[4]; bf16x8 v; } pf;
    pf.u[0] = cvt_pk_bf16(pA[0], pA[1]);
    pf.u[1] = cvt_pk_bf16(pA[2], pA[3]);
    pf.u[2] = cvt_pk_bf16(pB[0], pB[1]);
    pf.u[3] = cvt_pk_bf16(pB[2], pB[3]);

    bf16x8 v0 = *(const bf16x8*)&Vs[lr][kcol];
    bf16x8 v1 = *(const bf16x8*)&Vs[16 + lr][kcol];
    bf16x8 v2 = *(const bf16x8*)&Vs[32 + lr][kcol];
    bf16x8 v3 = *(const bf16x8*)&Vs[48 + lr][kcol];
    __builtin_amdgcn_s_setprio(1);
    acc0 = MFMA16(v0, pf.v, acc0);
    acc1 = MFMA16(v1, pf.v, acc1);
    acc2 = MFMA16(v2, pf.v, acc2);
    acc3 = MFMA16(v3, pf.v, acc3);
    __builtin_amdgcn_s_setprio(0);
  }

  ls += __shfl_xor(ls, 16, 64);
  ls += __shfl_xor(ls, 32, 64);

  if (kh == 1) {
    float* Lq = &Ls[qh][lr][0];
    *(f32x4*)(Lq + lg * 4) = acc0;
    *(f32x4*)(Lq + 16 + lg * 4) = acc1;
    *(f32x4*)(Lq + 32 + lg * 4) = acc2;
    *(f32x4*)(Lq + 48 + lg * 4) = acc3;
    if (lg == 0) lsb[qh][lr] = ls;
  }
  __syncthreads();
  if (kh == 0) {
    const float* Lq = &Ls[qh][lr][0];
    acc0 += *(const f32x4*)(Lq + lg * 4);
    acc1 += *(const f32x4*)(Lq + 16 + lg * 4);
    acc2 += *(const f32x4*)(Lq + 32 + lg * 4);
    acc3 += *(const f32x4*)(Lq + 48 + lg * 4);
    float inv = 1.f / (ls + lsb[qh][lr]);
    short* ob = Obf + qrow * 512 + hd * 64 + lg * 4;
    uint2 pk;
    pk.x = cvt_pk_bf16(acc0[0] * inv, acc0[1] * inv);
    pk.y = cvt_pk_bf16(acc0[2] * inv, acc0[3] * inv);
    *(uint2*)(ob) = pk;
    pk.x = cvt_pk_bf16(acc1[0] * inv, acc1[1] * inv);
    pk.y = cvt_pk_bf16(acc1[2] * inv, acc1[3] * inv);
    *(uint2*)(ob + 16) = pk;
    pk.x = cvt_pk_bf16(acc2[0] * inv, acc2[1] * inv);
    pk.y = cvt_pk_bf16(acc2[2] * inv, acc2[3] * inv);
    *(uint2*)(ob + 32) = pk;
    pk.x = cvt_pk_bf16(acc3[0] * inv, acc3[1] * inv);
    pk.y = cvt_pk_bf16(acc3[2] * inv, acc3[3] * inv);
    *(uint2*)(ob + 48) = pk;
  }
}

// ---------------- launch ----------------
extern "C" void kernel_launch(void* const* d_in, const int* in_sizes, int n_in,
                              void* d_out, int out_size, void* d_ws, size_t ws_size,
                              hipStream_t stream) {
  const float* x  = (const float*)d_in[0];
  const float* Wq = (const float*)d_in[1];
  const float* bq = (const float*)d_in[2];
  const float* Wk = (const float*)d_in[3];
  const float* bk = (const float*)d_in[4];
  const float* Wv = (const float*)d_in[5];
  const float* bv = (const float*)d_in[6];
  const float* Wo = (const float*)d_in[7];
  const float* bo = (const float*)d_in[8];
  float* out = (float*)d_out;
  float* ws  = (float*)d_ws;

  const size_t M1 = 1048576ull;  // 1M floats
  float* Qb    = ws;
  float* Kb    = ws + 2 * M1;
  short* Vt    = (short*)(ws + 4 * M1);
  short* xe_bf = (short*)(ws + 5 * M1);
  short* Qbf   = (short*)(ws + 5 * M1);      // reuse xe after gemm_qkv
  short* Wqbf  = (short*)(ws + 6 * M1);
  short* Wkbf  = (short*)(ws + 6 * M1 + 131072);
  short* Wvbf  = (short*)(ws + 6 * M1 + 262144);
  short* Wobf  = (short*)(ws + 6 * M1 + 393216);
  short* attn_out = (short*)(ws + 6 * M1 + 524288);
  short* Kbf = (short*)out;
  float* bb  = out + M1;
  float* q2h = out + M1 + 2048;
  float* k2h = out + M1 + 2048 + 32768;

  hipLaunchKernelGGL(prep_logmap, dim3(2562), dim3(256), 0, stream,
                     x, Wq, Wk, Wv, Wo, bq, bk, xe_bf, Wqbf, Wkbf, Wvbf, Wobf, bb);

  hipLaunchKernelGGL(gemm_qkv, dim3(8, 64, 3), dim3(256), 0, stream,
                     xe_bf, Wqbf, Wkbf, Wvbf, bv, Qb, Kb, Vt);

  hipLaunchKernelGGL(hyp_epilogue_v4, dim3(2048, 2), dim3(256), 0, stream,
                     Qb, Kb, bb, Qbf, Kbf, q2h, k2h);

  hipLaunchKernelGGL(attn_mfma_v6, dim3(512), dim3(512), 0, stream,
                     Qbf, Kbf, q2h, k2h, Vt, attn_out);

  hipLaunchKernelGGL(gemm_bf, dim3(8, 64), dim3(256), 0, stream, attn_out, Wobf, bo, out);
}

// Round 17
// 71.595 us; speedup vs baseline: 1.0552x; 1.0422x over previous
//
#include <hip/hip_runtime.h>
#include <math.h>

#define EPSF   1e-8f
#define CLAMPF 0.99999f   // 1 - 1e-5 (f32)

typedef __attribute__((ext_vector_type(8))) short bf16x8;
typedef __attribute__((ext_vector_type(4))) float f32x4;
#define MFMA16(a,b,c) __builtin_amdgcn_mfma_f32_16x16x32_bf16(a,b,c,0,0,0)

// hardware packed f32x2 -> bf16x2 (single VALU instr); low half = first arg
__device__ __forceinline__ unsigned cvt_pk_bf16(float lo, float hi) {
  unsigned r;
  asm("v_cvt_pk_bf16_f32 %0, %1, %2" : "=v"(r) : "v"(lo), "v"(hi));
  return r;
}

// async global->LDS DMA, 16B/lane, wave-uniform LDS base + lane*16 dest
typedef __attribute__((address_space(1))) const void GV;
typedef __attribute__((address_space(3))) void LV;
__device__ __forceinline__ void gload_lds16(const void* g, void* l) {
  __builtin_amdgcn_global_load_lds((GV*)g, (LV*)l, 16, 0, 0);
}

__device__ __forceinline__ float wave_sum64(float v) {
  v += __shfl_xor(v, 1, 64);
  v += __shfl_xor(v, 2, 64);
  v += __shfl_xor(v, 4, 64);
  v += __shfl_xor(v, 8, 64);
  v += __shfl_xor(v, 16, 64);
  v += __shfl_xor(v, 32, 64);
  return v;
}

// ---------------- fused prep: logmap 2 rows/block (id<2048) + weight bf16 (2048..2559) + bias_ball (2560..2561) ----------------
__global__ __launch_bounds__(256) void prep_logmap(const float* __restrict__ x,
                                                   const float* __restrict__ Wq,
                                                   const float* __restrict__ Wk,
                                                   const float* __restrict__ Wv,
                                                   const float* __restrict__ Wo,
                                                   const float* __restrict__ bq,
                                                   const float* __restrict__ bk,
                                                   short* __restrict__ xe,
                                                   short* __restrict__ Wqbf,
                                                   short* __restrict__ Wkbf,
                                                   short* __restrict__ Wvbf,
                                                   short* __restrict__ Wobf,
                                                   float* __restrict__ bb) {
  const int id = blockIdx.x;
  const int t = threadIdx.x;
  __shared__ float red[4];
  if (id < 2048) {
    const int half = t >> 7, tc = t & 127;
    const int row = id * 2 + half;
    float4 v = ((const float4*)(x + (size_t)row * 512))[tc];
    float s = wave_sum64(v.x * v.x + v.y * v.y + v.z * v.z + v.w * v.w);
    if ((t & 63) == 0) red[t >> 6] = s;
    __syncthreads();
    float n2 = red[half * 2] + red[half * 2 + 1];
    float n = sqrtf(n2);
    float nm = fmaxf(n, EPSF);
    float a = fminf(nm, 1.0f);
    float at = 0.5f * logf((1.f + a) / (1.f - a));
    float sc = at / nm;
    uint2 o;
    o.x = cvt_pk_bf16(v.x * sc, v.y * sc);
    o.y = cvt_pk_bf16(v.z * sc, v.w * sc);
    ((uint2*)(xe + (size_t)row * 512))[tc] = o;
    return;
  }
  const int wid = id - 2048;
  if (wid < 512) {
    const int which = wid >> 7, chunk = wid & 127;
    const float* src; short* dst;
    switch (which) {
      case 0: src = Wq; dst = Wqbf; break;
      case 1: src = Wk; dst = Wkbf; break;
      case 2: src = Wv; dst = Wvbf; break;
      default: src = Wo; dst = Wobf; break;
    }
    const int idx = chunk * 2048 + t * 8;
    float4 a = *(const float4*)(src + idx);
    float4 b2 = *(const float4*)(src + idx + 4);
    union { int4 v; unsigned u[4]; } o;
    o.u[0] = cvt_pk_bf16(a.x, a.y);
    o.u[1] = cvt_pk_bf16(a.z, a.w);
    o.u[2] = cvt_pk_bf16(b2.x, b2.y);
    o.u[3] = cvt_pk_bf16(b2.z, b2.w);
    *(int4*)(dst + idx) = o.v;
    return;
  }
  // bias_ball = expmap0(b); 520 floats each
  const int which = wid - 512;
  const float* b = which ? bk : bq;
  float* o = bb + (size_t)which * 520;
  float2 v = ((const float2*)b)[t];
  float s = wave_sum64(v.x * v.x + v.y * v.y);
  if ((t & 63) == 0) red[t >> 6] = s;
  __syncthreads();
  float n2 = red[0] + red[1] + red[2] + red[3];
  float n = sqrtf(n2);
  float nm = fmaxf(n, EPSF);
  float tt = fminf(nm, 15.f);
  float f = tanhf(tt) / nm;
  float on = f * nm;
  if (on > CLAMPF) f *= CLAMPF / on;
  ((float2*)o)[t] = make_float2(f * v.x, f * v.y);
  if (t == 0) o[512] = f * f * n2;
}

// ---------------- bf16 MFMA GEMM core, 64x64 tile, global_load_lds staging (r14 verified) ----------------
template <int VT>
__device__ __forceinline__ void gemm_core(const short* __restrict__ A,
                                          const short* __restrict__ W,
                                          const float* __restrict__ bias,
                                          void* __restrict__ outp,
                                          int bx, int by) {
  __shared__ __align__(16) short As[64][64];
  __shared__ __align__(16) short Ws[64][64];
  const int t = threadIdx.x;
  const int wave = t >> 6, lane = t & 63, lg = lane >> 4, lr = lane & 15;
  const int mh = wave & 1, nh = wave >> 1;
  f32x4 z = {0.f, 0.f, 0.f, 0.f};
  f32x4 acc00 = z, acc01 = z, acc10 = z, acc11 = z;

  const int rsub = lane >> 3;
  const int swz = ((lane & 7) ^ rsub) * 8;      // shorts
  const short* Ag0 = A + (size_t)(by * 64 + wave * 16 + rsub) * 512 + swz;
  const short* Ag1 = Ag0 + 8 * 512;
  const short* Wg0 = W + (size_t)(bx * 64 + wave * 16 + rsub) * 512 + swz;
  const short* Wg1 = Wg0 + 8 * 512;
  short* Al0 = &As[wave * 16][0];
  short* Al1 = &As[wave * 16 + 8][0];
  short* Wl0 = &Ws[wave * 16][0];
  short* Wl1 = &Ws[wave * 16 + 8][0];

  const int ra = mh * 32 + lr;
  const int rb = nh * 32 + lr;
  const int cx = (lr & 7) * 8;

  for (int kt = 0; kt < 512; kt += 64) {
    __syncthreads();
    gload_lds16(Ag0 + kt, Al0);
    gload_lds16(Ag1 + kt, Al1);
    gload_lds16(Wg0 + kt, Wl0);
    gload_lds16(Wg1 + kt, Wl1);
    __syncthreads();
#pragma unroll
    for (int kk = 0; kk < 2; ++kk) {
      const int c = (kk * 32 + lg * 8) ^ cx;
      bf16x8 af0 = *(const bf16x8*)&As[ra][c];
      bf16x8 af1 = *(const bf16x8*)&As[ra + 16][c];
      bf16x8 bf0 = *(const bf16x8*)&Ws[rb][c];
      bf16x8 bf1 = *(const bf16x8*)&Ws[rb + 16][c];
      acc00 = MFMA16(af0, bf0, acc00);
      acc01 = MFMA16(af0, bf1, acc01);
      acc10 = MFMA16(af1, bf0, acc10);
      acc11 = MFMA16(af1, bf1, acc11);
    }
  }

  if (VT == 0) {
    float* out = (float*)outp;
    float b0 = 0.f, b1 = 0.f;
    if (bias) { b0 = bias[bx * 64 + nh * 32 + lr]; b1 = bias[bx * 64 + nh * 32 + 16 + lr]; }
#pragma unroll
    for (int r = 0; r < 4; ++r) {
      size_t row0 = (size_t)(by * 64 + mh * 32 + lg * 4 + r);
      size_t row1 = row0 + 16;
      out[row0 * 512 + bx * 64 + nh * 32 + lr] = acc00[r] + b0;
      out[row0 * 512 + bx * 64 + nh * 32 + 16 + lr] = acc01[r] + b1;
      out[row1 * 512 + bx * 64 + nh * 32 + lr] = acc10[r] + b0;
      out[row1 * 512 + bx * 64 + nh * 32 + 16 + lr] = acc11[r] + b1;
    }
  } else {
    short* vt = (short*)outp;
    const int bidx = by >> 4;
    const int trow0 = (by & 15) * 64 + mh * 32 + lg * 4;
    const int c0 = bx * 64 + nh * 32 + lr;
    const int c1 = c0 + 16;
    const float b0 = bias[c0], b1 = bias[c1];
    size_t base0 = ((size_t)(bidx * 8 + (c0 >> 6)) * 64 + (c0 & 63)) * 1024;
    size_t base1 = ((size_t)(bidx * 8 + (c1 >> 6)) * 64 + (c1 & 63)) * 1024;
    uint2 pk;
    pk.x = cvt_pk_bf16(acc00[0] + b0, acc00[1] + b0);
    pk.y = cvt_pk_bf16(acc00[2] + b0, acc00[3] + b0);
    *(uint2*)(vt + base0 + trow0) = pk;
    pk.x = cvt_pk_bf16(acc01[0] + b1, acc01[1] + b1);
    pk.y = cvt_pk_bf16(acc01[2] + b1, acc01[3] + b1);
    *(uint2*)(vt + base1 + trow0) = pk;
    pk.x = cvt_pk_bf16(acc10[0] + b0, acc10[1] + b0);
    pk.y = cvt_pk_bf16(acc10[2] + b0, acc10[3] + b0);
    *(uint2*)(vt + base0 + trow0 + 16) = pk;
    pk.x = cvt_pk_bf16(acc11[0] + b1, acc11[1] + b1);
    pk.y = cvt_pk_bf16(acc11[2] + b1, acc11[3] + b1);
    *(uint2*)(vt + base1 + trow0 + 16) = pk;
  }
}

__global__ __launch_bounds__(256) void gemm_qkv(const short* __restrict__ A,
                                                const short* __restrict__ Wq,
                                                const short* __restrict__ Wk,
                                                const short* __restrict__ Wv,
                                                const float* __restrict__ bv,
                                                float* __restrict__ Qo,
                                                float* __restrict__ Ko,
                                                short* __restrict__ Vt) {
  switch (blockIdx.z) {
    case 0: gemm_core<0>(A, Wq, nullptr, Qo, blockIdx.x, blockIdx.y); break;
    case 1: gemm_core<0>(A, Wk, nullptr, Ko, blockIdx.x, blockIdx.y); break;
    default: gemm_core<1>(A, Wv, bv, Vt, blockIdx.x, blockIdx.y); break;
  }
}

__global__ __launch_bounds__(256) void gemm_bf(const short* __restrict__ A,
                                               const short* __restrict__ W,
                                               const float* __restrict__ bias,
                                               float* __restrict__ out) {
  gemm_core<0>(A, W, bias, out, blockIdx.x, blockIdx.y);
}

// ---------------- hyperbolic epilogue v4: 2 rows/block, float4 (r13 verified) ----------------
__global__ __launch_bounds__(256) void hyp_epilogue_v4(const float* __restrict__ Qb,
                                                       const float* __restrict__ Kb,
                                                       const float* __restrict__ bbase,
                                                       short* __restrict__ Qbf,
                                                       short* __restrict__ Kbf,
                                                       float* __restrict__ q2h,
                                                       float* __restrict__ k2h) {
  const int which = blockIdx.y;
  const float* Y = which ? Kb : Qb;
  const float* bb = bbase + (size_t)which * 520;
  short* Ybf = which ? Kbf : Qbf;
  float* y2h = which ? k2h : q2h;
  const int t = threadIdx.x;
  const int half = t >> 7, tc = t & 127;
  const int row = blockIdx.x * 2 + half;

  float4 y = ((const float4*)(Y + (size_t)row * 512))[tc];
  float4 w = ((const float4*)bb)[tc];
  __shared__ float red[8];
  float sn = wave_sum64(y.x * y.x + y.y * y.y + y.z * y.z + y.w * y.w);
  float sd = wave_sum64(y.x * w.x + y.y * w.y + y.z * w.z + y.w * w.w);
  if ((t & 63) == 0) { red[t >> 6] = sn; red[4 + (t >> 6)] = sd; }
  __syncthreads();
  float n2 = red[half * 2] + red[half * 2 + 1];
  float dt = red[4 + half * 2] + red[4 + half * 2 + 1];
  float y2 = bb[512];
  float n = sqrtf(n2);
  float nm = fmaxf(n, EPSF);
  float tt = fminf(nm, 15.f);
  float f = tanhf(tt) / nm;
  float on = f * nm;
  if (on > CLAMPF) f *= CLAMPF / on;
  float x2 = f * f * n2;
  float xy = f * dt;
  float A = 1.f + 2.f * xy + y2;
  float Bc = 1.f - x2;
  float den = fmaxf(1.f + 2.f * xy + x2 * y2, EPSF);
  float num2 = A * A * x2 + Bc * Bc * y2 + 2.f * A * Bc * xy;
  float nn = sqrtf(fmaxf(num2, 0.f)) / den;
  float nnm = fmaxf(nn, EPSF);
  float s2 = (nnm > CLAMPF) ? (CLAMPF / nnm) : 1.f;
  float g = s2 / den;
  float ox = g * (A * f * y.x + Bc * w.x);
  float oy = g * (A * f * y.y + Bc * w.y);
  float oz = g * (A * f * y.z + Bc * w.z);
  float ow = g * (A * f * y.w + Bc * w.w);
  uint2 o;
  o.x = cvt_pk_bf16(ox, oy);
  o.y = cvt_pk_bf16(oz, ow);
  ((uint2*)(Ybf + (size_t)row * 512))[tc] = o;
  float hs = ox * ox + oy * oy + oz * oz + ow * ow;
  hs += __shfl_xor(hs, 1, 64);
  hs += __shfl_xor(hs, 2, 64);
  hs += __shfl_xor(hs, 4, 64);
  hs += __shfl_xor(hs, 8, 64);
  if ((tc & 15) == 0) y2h[(size_t)(tc >> 4) * 4096 + row] = hs;
}

// ---------------- MFMA flash attention v8: v6 structure + simplified score math ----------------
// Identity (verified): den^2 - num2 = (1-q2)(1-k2)*den, den = 1 + q2*k2 - 2d.
// => num2 = den*(den - bc*mk), u = bc*mk*den/(den+sq)^2; the per-query bc^{1/8}
// factor cancels in softmax, so p' = exp2(max(0.125*log2(mk*den) - 0.25*log2(den+sq), Xmin)),
// Xmin = 0.125*(log2(u0) - log2(bc)) preserves the u >= u0 clamp exactly.
// k2s stores mk = 1-k2. Everything else identical to r12/r16-verified v6.
__global__ __launch_bounds__(512, 2) void attn_mfma_v8(const short* __restrict__ Qbf,
                                                       const short* __restrict__ Kbf,
                                                       const float* __restrict__ q2h,
                                                       const float* __restrict__ k2h,
                                                       const short* __restrict__ Vt,
                                                       short* __restrict__ Obf) {
  __shared__ __align__(16) short Ks[64][72];
  __shared__ __align__(16) short Vs[64][72];
  __shared__ __align__(16) float k2s[64];
  __shared__ __align__(16) float Ls[4][16][68];
  __shared__ float lsb[4][16];

  const int t = threadIdx.x;
  const int id = blockIdx.x;               // id = qt*32 + b*8 + hd
  const int qt = id >> 5;                  // 0..15 (64-query tiles)
  const int pr = (((id >> 3) & 3) << 3) | (id & 7);
  const int hd = pr & 7, b = pr >> 3;
  const int wave = t >> 6, lane = t & 63, lg = lane >> 4, lr = lane & 15;
  const int qh = wave >> 1, kh = wave & 1;

  const size_t qrow = (size_t)(b * 1024 + qt * 64 + qh * 16 + lr);
  const bf16x8 qf0 = *(const bf16x8*)(Qbf + qrow * 512 + hd * 64 + lg * 8);
  const bf16x8 qf1 = *(const bf16x8*)(Qbf + qrow * 512 + hd * 64 + 32 + lg * 8);

  const float q2 = q2h[(size_t)hd * 4096 + b * 1024 + qt * 64 + qh * 16 + lr];
  const float bc = 1.f - q2;               // > 0 (norms clamped < 1)
  const float q2p1 = 1.f + q2;
  // log2(u0) with u0 = 5.000025e-6 (the n<=0.99999 clamp)
  const float Xmin = 0.125f * (-17.6096137f - __builtin_amdgcn_logf(bc));

  const int sr = t >> 3, q8 = t & 7;
  const int p32 = sr & 31;
  const int kwr = (sr & 32) | (((p32 >> 2) & 1) << 4) | (((p32 >> 3) & 3) << 2) | (p32 & 3);
  const short* kgp = Kbf + (size_t)(b * 1024 + sr) * 512 + hd * 64 + q8 * 8;
  const short* vgp = Vt + ((size_t)(b * 8 + hd) * 64 + sr) * 1024 + q8 * 8;
  const float* k2gp = k2h + (size_t)hd * 4096 + b * 1024 + t;

  int4 rk0 = *(const int4*)kgp;
  int4 rv0 = *(const int4*)vgp;
  float rk2 = (t < 64) ? (1.f - *k2gp) : 0.f;   // mk = 1 - k2

  f32x4 z = {0.f, 0.f, 0.f, 0.f};
  f32x4 acc0 = z, acc1 = z, acc2 = z, acc3 = z;
  float ls = 0.f;
  const int krow = kh * 32 + lr;
  const int kcol = kh * 32 + lg * 8;

  for (int kt = 0; kt < 16; ++kt) {
    __syncthreads();
    *(int4*)&Ks[kwr][q8 * 8] = rk0;
    *(int4*)&Vs[sr][q8 * 8] = rv0;
    if (t < 64) k2s[t] = rk2;
    __syncthreads();
    if (kt < 15) {
      kgp += 64 * 512; vgp += 64; k2gp += 64;
      rk0 = *(const int4*)kgp;
      rv0 = *(const int4*)vgp;
      if (t < 64) rk2 = 1.f - *k2gp;
    }

    bf16x8 kf0 = *(const bf16x8*)&Ks[krow][lg * 8];
    bf16x8 kf1 = *(const bf16x8*)&Ks[krow][32 + lg * 8];
    bf16x8 kg0 = *(const bf16x8*)&Ks[krow + 16][lg * 8];
    bf16x8 kg1 = *(const bf16x8*)&Ks[krow + 16][32 + lg * 8];
    __builtin_amdgcn_s_setprio(1);
    f32x4 sA = MFMA16(kf0, qf0, z);
    sA = MFMA16(kf1, qf1, sA);
    f32x4 sB = MFMA16(kg0, qf0, z);
    sB = MFMA16(kg1, qf1, sB);
    __builtin_amdgcn_s_setprio(0);

    float pA[4], pB[4];
#pragma unroll
    for (int r = 0; r < 4; ++r) {
      float d = sA[r];
      float mk = k2s[kh * 32 + lg * 8 + r];
      float den = fmaxf(fmaf(-2.f, d, fmaf(-q2, mk, q2p1)), EPSF);  // 1+q2*k2-2d
      float t1 = fmaxf(fmaf(-bc, mk, den), 0.f);                     // den - bc*mk
      float sq = __builtin_amdgcn_sqrtf(den * t1);                   // sqrt(num2)
      float vv = den + sq;
      float wv = mk * den;
      float X = fmaf(0.125f, __builtin_amdgcn_logf(wv),
                     -0.25f * __builtin_amdgcn_logf(vv));
      pA[r] = __builtin_amdgcn_exp2f(fmaxf(X, Xmin));
    }
#pragma unroll
    for (int r = 0; r < 4; ++r) {
      float d = sB[r];
      float mk = k2s[kh * 32 + lg * 8 + 4 + r];
      float den = fmaxf(fmaf(-2.f, d, fmaf(-q2, mk, q2p1)), EPSF);
      float t1 = fmaxf(fmaf(-bc, mk, den), 0.f);
      float sq = __builtin_amdgcn_sqrtf(den * t1);
      float vv = den + sq;
      float wv = mk * den;
      float X = fmaf(0.125f, __builtin_amdgcn_logf(wv),
                     -0.25f * __builtin_amdgcn_logf(vv));
      pB[r] = __builtin_amdgcn_exp2f(fmaxf(X, Xmin));
    }
    ls += (pA[0] + pA[1] + pA[2] + pA[3]) + (pB[0] + pB[1] + pB[2] + pB[3]);

    union { unsigned u[4]; bf16x8 v; } pf;
    pf.u[0] = cvt_pk_bf16(pA[0], pA[1]);
    pf.u[1] = cvt_pk_bf16(pA[2], pA[3]);
    pf.u[2] = cvt_pk_bf16(pB[0], pB[1]);
    pf.u[3] = cvt_pk_bf16(pB[2], pB[3]);

    bf16x8 v0 = *(const bf16x8*)&Vs[lr][kcol];
    bf16x8 v1 = *(const bf16x8*)&Vs[16 + lr][kcol];
    bf16x8 v2 = *(const bf16x8*)&Vs[32 + lr][kcol];
    bf16x8 v3 = *(const bf16x8*)&Vs[48 + lr][kcol];
    __builtin_amdgcn_s_setprio(1);
    acc0 = MFMA16(v0, pf.v, acc0);
    acc1 = MFMA16(v1, pf.v, acc1);
    acc2 = MFMA16(v2, pf.v, acc2);
    acc3 = MFMA16(v3, pf.v, acc3);
    __builtin_amdgcn_s_setprio(0);
  }

  ls += __shfl_xor(ls, 16, 64);
  ls += __shfl_xor(ls, 32, 64);

  if (kh == 1) {
    float* Lq = &Ls[qh][lr][0];
    *(f32x4*)(Lq + lg * 4) = acc0;
    *(f32x4*)(Lq + 16 + lg * 4) = acc1;
    *(f32x4*)(Lq + 32 + lg * 4) = acc2;
    *(f32x4*)(Lq + 48 + lg * 4) = acc3;
    if (lg == 0) lsb[qh][lr] = ls;
  }
  __syncthreads();
  if (kh == 0) {
    const float* Lq = &Ls[qh][lr][0];
    acc0 += *(const f32x4*)(Lq + lg * 4);
    acc1 += *(const f32x4*)(Lq + 16 + lg * 4);
    acc2 += *(const f32x4*)(Lq + 32 + lg * 4);
    acc3 += *(const f32x4*)(Lq + 48 + lg * 4);
    float inv = 1.f / (ls + lsb[qh][lr]);
    short* ob = Obf + qrow * 512 + hd * 64 + lg * 4;
    uint2 pk;
    pk.x = cvt_pk_bf16(acc0[0] * inv, acc0[1] * inv);
    pk.y = cvt_pk_bf16(acc0[2] * inv, acc0[3] * inv);
    *(uint2*)(ob) = pk;
    pk.x = cvt_pk_bf16(acc1[0] * inv, acc1[1] * inv);
    pk.y = cvt_pk_bf16(acc1[2] * inv, acc1[3] * inv);
    *(uint2*)(ob + 16) = pk;
    pk.x = cvt_pk_bf16(acc2[0] * inv, acc2[1] * inv);
    pk.y = cvt_pk_bf16(acc2[2] * inv, acc2[3] * inv);
    *(uint2*)(ob + 32) = pk;
    pk.x = cvt_pk_bf16(acc3[0] * inv, acc3[1] * inv);
    pk.y = cvt_pk_bf16(acc3[2] * inv, acc3[3] * inv);
    *(uint2*)(ob + 48) = pk;
  }
}

// ---------------- launch ----------------
extern "C" void kernel_launch(void* const* d_in, const int* in_sizes, int n_in,
                              void* d_out, int out_size, void* d_ws, size_t ws_size,
                              hipStream_t stream) {
  const float* x  = (const float*)d_in[0];
  const float* Wq = (const float*)d_in[1];
  const float* bq = (const float*)d_in[2];
  const float* Wk = (const float*)d_in[3];
  const float* bk = (const float*)d_in[4];
  const float* Wv = (const float*)d_in[5];
  const float* bv = (const float*)d_in[6];
  const float* Wo = (const float*)d_in[7];
  const float* bo = (const float*)d_in[8];
  float* out = (float*)d_out;
  float* ws  = (float*)d_ws;

  const size_t M1 = 1048576ull;  // 1M floats
  float* Qb    = ws;
  float* Kb    = ws + 2 * M1;
  short* Vt    = (short*)(ws + 4 * M1);
  short* xe_bf = (short*)(ws + 5 * M1);
  short* Qbf   = (short*)(ws + 5 * M1);      // reuse xe after gemm_qkv
  short* Wqbf  = (short*)(ws + 6 * M1);
  short* Wkbf  = (short*)(ws + 6 * M1 + 131072);
  short* Wvbf  = (short*)(ws + 6 * M1 + 262144);
  short* Wobf  = (short*)(ws + 6 * M1 + 393216);
  short* attn_out = (short*)(ws + 6 * M1 + 524288);
  short* Kbf = (short*)out;
  float* bb  = out + M1;
  float* q2h = out + M1 + 2048;
  float* k2h = out + M1 + 2048 + 32768;

  hipLaunchKernelGGL(prep_logmap, dim3(2562), dim3(256), 0, stream,
                     x, Wq, Wk, Wv, Wo, bq, bk, xe_bf, Wqbf, Wkbf, Wvbf, Wobf, bb);

  hipLaunchKernelGGL(gemm_qkv, dim3(8, 64, 3), dim3(256), 0, stream,
                     xe_bf, Wqbf, Wkbf, Wvbf, bv, Qb, Kb, Vt);

  hipLaunchKernelGGL(hyp_epilogue_v4, dim3(2048, 2), dim3(256), 0, stream,
                     Qb, Kb, bb, Qbf, Kbf, q2h, k2h);

  hipLaunchKernelGGL(attn_mfma_v8, dim3(512), dim3(512), 0, stream,
                     Qbf, Kbf, q2h, k2h, Vt, attn_out);

  hipLaunchKernelGGL(gemm_bf, dim3(8, 64), dim3(256), 0, stream, attn_out, Wobf, bo, out);
}

// Round 18
// 67.820 us; speedup vs baseline: 1.1139x; 1.0557x over previous
//
#include <hip/hip_runtime.h>
#include <math.h>

#define EPSF   1e-8f
#define CLAMPF 0.99999f   // 1 - 1e-5 (f32)

typedef __attribute__((ext_vector_type(8))) short bf16x8;
typedef __attribute__((ext_vector_type(4))) float f32x4;
#define MFMA16(a,b,c) __builtin_amdgcn_mfma_f32_16x16x32_bf16(a,b,c,0,0,0)

// hardware packed f32x2 -> bf16x2 (single VALU instr); low half = first arg
__device__ __forceinline__ unsigned cvt_pk_bf16(float lo, float hi) {
  unsigned r;
  asm("v_cvt_pk_bf16_f32 %0, %1, %2" : "=v"(r) : "v"(lo), "v"(hi));
  return r;
}

// async global->LDS DMA, 16B/lane, wave-uniform LDS base + lane*16 dest
typedef __attribute__((address_space(1))) const void GV;
typedef __attribute__((address_space(3))) void LV;
__device__ __forceinline__ void gload_lds16(const void* g, void* l) {
  __builtin_amdgcn_global_load_lds((GV*)g, (LV*)l, 16, 0, 0);
}

__device__ __forceinline__ float wave_sum64(float v) {
  v += __shfl_xor(v, 1, 64);
  v += __shfl_xor(v, 2, 64);
  v += __shfl_xor(v, 4, 64);
  v += __shfl_xor(v, 8, 64);
  v += __shfl_xor(v, 16, 64);
  v += __shfl_xor(v, 32, 64);
  return v;
}

// ---------------- fused prep: logmap 2 rows/block (id<2048) + weight bf16 (2048..2559) + bias_ball (2560..2561) ----------------
__global__ __launch_bounds__(256) void prep_logmap(const float* __restrict__ x,
                                                   const float* __restrict__ Wq,
                                                   const float* __restrict__ Wk,
                                                   const float* __restrict__ Wv,
                                                   const float* __restrict__ Wo,
                                                   const float* __restrict__ bq,
                                                   const float* __restrict__ bk,
                                                   short* __restrict__ xe,
                                                   short* __restrict__ Wqbf,
                                                   short* __restrict__ Wkbf,
                                                   short* __restrict__ Wvbf,
                                                   short* __restrict__ Wobf,
                                                   float* __restrict__ bb) {
  const int id = blockIdx.x;
  const int t = threadIdx.x;
  __shared__ float red[4];
  if (id < 2048) {
    const int half = t >> 7, tc = t & 127;
    const int row = id * 2 + half;
    float4 v = ((const float4*)(x + (size_t)row * 512))[tc];
    float s = wave_sum64(v.x * v.x + v.y * v.y + v.z * v.z + v.w * v.w);
    if ((t & 63) == 0) red[t >> 6] = s;
    __syncthreads();
    float n2 = red[half * 2] + red[half * 2 + 1];
    float n = sqrtf(n2);
    float nm = fmaxf(n, EPSF);
    float a = fminf(nm, 1.0f);
    float at = 0.5f * logf((1.f + a) / (1.f - a));
    float sc = at / nm;
    uint2 o;
    o.x = cvt_pk_bf16(v.x * sc, v.y * sc);
    o.y = cvt_pk_bf16(v.z * sc, v.w * sc);
    ((uint2*)(xe + (size_t)row * 512))[tc] = o;
    return;
  }
  const int wid = id - 2048;
  if (wid < 512) {
    const int which = wid >> 7, chunk = wid & 127;
    const float* src; short* dst;
    switch (which) {
      case 0: src = Wq; dst = Wqbf; break;
      case 1: src = Wk; dst = Wkbf; break;
      case 2: src = Wv; dst = Wvbf; break;
      default: src = Wo; dst = Wobf; break;
    }
    const int idx = chunk * 2048 + t * 8;
    float4 a = *(const float4*)(src + idx);
    float4 b2 = *(const float4*)(src + idx + 4);
    union { int4 v; unsigned u[4]; } o;
    o.u[0] = cvt_pk_bf16(a.x, a.y);
    o.u[1] = cvt_pk_bf16(a.z, a.w);
    o.u[2] = cvt_pk_bf16(b2.x, b2.y);
    o.u[3] = cvt_pk_bf16(b2.z, b2.w);
    *(int4*)(dst + idx) = o.v;
    return;
  }
  // bias_ball = expmap0(b); 520 floats each
  const int which = wid - 512;
  const float* b = which ? bk : bq;
  float* o = bb + (size_t)which * 520;
  float2 v = ((const float2*)b)[t];
  float s = wave_sum64(v.x * v.x + v.y * v.y);
  if ((t & 63) == 0) red[t >> 6] = s;
  __syncthreads();
  float n2 = red[0] + red[1] + red[2] + red[3];
  float n = sqrtf(n2);
  float nm = fmaxf(n, EPSF);
  float tt = fminf(nm, 15.f);
  float f = tanhf(tt) / nm;
  float on = f * nm;
  if (on > CLAMPF) f *= CLAMPF / on;
  ((float2*)o)[t] = make_float2(f * v.x, f * v.y);
  if (t == 0) o[512] = f * f * n2;
}

// ---------------- bf16 MFMA GEMM core, 128x64 tile (M x N), gload_lds staging ----------------
// r11-verified indexing + r14-verified swizzled DMA staging. 4 waves: mh = wave&1 (M 64-half),
// nh = wave>>1 (N 32-half); wave computes 64x32 via acc[4][2]. BK=64.
// VT==0: fp32 out [4096][512]. VT==1: bf16 transposed Vt[b][h][dv][t] with bias.
template <int VT>
__device__ __forceinline__ void gemm_core128(const short* __restrict__ A,
                                             const short* __restrict__ W,
                                             const float* __restrict__ bias,
                                             void* __restrict__ outp,
                                             int bx, int by) {
  __shared__ __align__(16) short As[128][64];
  __shared__ __align__(16) short Ws[64][64];
  const int t = threadIdx.x;
  const int wave = t >> 6, lane = t & 63, lg = lane >> 4, lr = lane & 15;
  const int mh = wave & 1, nh = wave >> 1;
  f32x4 z = {0.f, 0.f, 0.f, 0.f};
  f32x4 acc[4][2];
#pragma unroll
  for (int i = 0; i < 4; ++i) { acc[i][0] = z; acc[i][1] = z; }

  // staging: wave stages A rows [wave*32,+32) (4 gloads) and W rows [wave*16,+16) (2 gloads)
  const int rsub = lane >> 3;
  const int swz = ((lane & 7) ^ rsub) * 8;      // shorts (pre-swizzled global col)
  const short* Ag0 = A + (size_t)(by * 128 + wave * 32 + rsub) * 512 + swz;
  const short* Wg0 = W + (size_t)(bx * 64 + wave * 16 + rsub) * 512 + swz;
  short* Al0 = &As[wave * 32][0];
  short* Al1 = &As[wave * 32 + 8][0];
  short* Al2 = &As[wave * 32 + 16][0];
  short* Al3 = &As[wave * 32 + 24][0];
  short* Wl0 = &Ws[wave * 16][0];
  short* Wl1 = &Ws[wave * 16 + 8][0];

  const int rb = nh * 32 + lr;
  const int cx = (lr & 7) * 8;                  // read-side swizzle term

  for (int kt = 0; kt < 512; kt += 64) {
    __syncthreads();
    gload_lds16(Ag0 + kt, Al0);
    gload_lds16(Ag0 + kt + 8 * 512, Al1);
    gload_lds16(Ag0 + kt + 16 * 512, Al2);
    gload_lds16(Ag0 + kt + 24 * 512, Al3);
    gload_lds16(Wg0 + kt, Wl0);
    gload_lds16(Wg0 + kt + 8 * 512, Wl1);
    __syncthreads();
#pragma unroll
    for (int kk = 0; kk < 2; ++kk) {
      const int c = (kk * 32 + lg * 8) ^ cx;
      bf16x8 bf0 = *(const bf16x8*)&Ws[rb][c];
      bf16x8 bf1 = *(const bf16x8*)&Ws[rb + 16][c];
#pragma unroll
      for (int i = 0; i < 4; ++i) {
        bf16x8 af = *(const bf16x8*)&As[mh * 64 + i * 16 + lr][c];
        acc[i][0] = MFMA16(af, bf0, acc[i][0]);
        acc[i][1] = MFMA16(af, bf1, acc[i][1]);
      }
    }
  }

  if (VT == 0) {
    float* out = (float*)outp;
    float b0 = 0.f, b1 = 0.f;
    if (bias) { b0 = bias[bx * 64 + nh * 32 + lr]; b1 = bias[bx * 64 + nh * 32 + 16 + lr]; }
#pragma unroll
    for (int i = 0; i < 4; ++i) {
#pragma unroll
      for (int r = 0; r < 4; ++r) {
        size_t row = (size_t)(by * 128 + mh * 64 + i * 16 + lg * 4 + r);
        out[row * 512 + bx * 64 + nh * 32 + lr]      = acc[i][0][r] + b0;
        out[row * 512 + bx * 64 + nh * 32 + 16 + lr] = acc[i][1][r] + b1;
      }
    }
  } else {
    // r11-verified transposed bf16 store for 128-row tiles
    short* vt = (short*)outp;
    const int bidx = by >> 3;                       // batch (1024 tokens = 8 by-blocks)
    const int tokb = (by & 7) * 128 + mh * 64;      // token base within batch
    const int c0 = bx * 64 + nh * 32 + lr;
    const int c1 = c0 + 16;
    const float b0 = bias[c0], b1 = bias[c1];
    size_t base0 = ((size_t)(bidx * 8 + (c0 >> 6)) * 64 + (c0 & 63)) * 1024;
    size_t base1 = ((size_t)(bidx * 8 + (c1 >> 6)) * 64 + (c1 & 63)) * 1024;
#pragma unroll
    for (int i = 0; i < 4; ++i) {
      const int tok0 = tokb + i * 16 + lg * 4;
      uint2 pk;
      pk.x = cvt_pk_bf16(acc[i][0][0] + b0, acc[i][0][1] + b0);
      pk.y = cvt_pk_bf16(acc[i][0][2] + b0, acc[i][0][3] + b0);
      *(uint2*)(vt + base0 + tok0) = pk;
      pk.x = cvt_pk_bf16(acc[i][1][0] + b1, acc[i][1][1] + b1);
      pk.y = cvt_pk_bf16(acc[i][1][2] + b1, acc[i][1][3] + b1);
      *(uint2*)(vt + base1 + tok0) = pk;
    }
  }
}

// ---------------- bf16 MFMA GEMM core, 64x64 tile, gload_lds staging (r14 verified) ----------------
__device__ __forceinline__ void gemm_core64(const short* __restrict__ A,
                                            const short* __restrict__ W,
                                            const float* __restrict__ bias,
                                            float* __restrict__ out,
                                            int bx, int by) {
  __shared__ __align__(16) short As[64][64];
  __shared__ __align__(16) short Ws[64][64];
  const int t = threadIdx.x;
  const int wave = t >> 6, lane = t & 63, lg = lane >> 4, lr = lane & 15;
  const int mh = wave & 1, nh = wave >> 1;
  f32x4 z = {0.f, 0.f, 0.f, 0.f};
  f32x4 acc00 = z, acc01 = z, acc10 = z, acc11 = z;

  const int rsub = lane >> 3;
  const int swz = ((lane & 7) ^ rsub) * 8;
  const short* Ag0 = A + (size_t)(by * 64 + wave * 16 + rsub) * 512 + swz;
  const short* Ag1 = Ag0 + 8 * 512;
  const short* Wg0 = W + (size_t)(bx * 64 + wave * 16 + rsub) * 512 + swz;
  const short* Wg1 = Wg0 + 8 * 512;
  short* Al0 = &As[wave * 16][0];
  short* Al1 = &As[wave * 16 + 8][0];
  short* Wl0 = &Ws[wave * 16][0];
  short* Wl1 = &Ws[wave * 16 + 8][0];

  const int ra = mh * 32 + lr;
  const int rb = nh * 32 + lr;
  const int cx = (lr & 7) * 8;

  for (int kt = 0; kt < 512; kt += 64) {
    __syncthreads();
    gload_lds16(Ag0 + kt, Al0);
    gload_lds16(Ag1 + kt, Al1);
    gload_lds16(Wg0 + kt, Wl0);
    gload_lds16(Wg1 + kt, Wl1);
    __syncthreads();
#pragma unroll
    for (int kk = 0; kk < 2; ++kk) {
      const int c = (kk * 32 + lg * 8) ^ cx;
      bf16x8 af0 = *(const bf16x8*)&As[ra][c];
      bf16x8 af1 = *(const bf16x8*)&As[ra + 16][c];
      bf16x8 bf0 = *(const bf16x8*)&Ws[rb][c];
      bf16x8 bf1 = *(const bf16x8*)&Ws[rb + 16][c];
      acc00 = MFMA16(af0, bf0, acc00);
      acc01 = MFMA16(af0, bf1, acc01);
      acc10 = MFMA16(af1, bf0, acc10);
      acc11 = MFMA16(af1, bf1, acc11);
    }
  }

  float b0 = 0.f, b1 = 0.f;
  if (bias) { b0 = bias[bx * 64 + nh * 32 + lr]; b1 = bias[bx * 64 + nh * 32 + 16 + lr]; }
#pragma unroll
  for (int r = 0; r < 4; ++r) {
    size_t row0 = (size_t)(by * 64 + mh * 32 + lg * 4 + r);
    size_t row1 = row0 + 16;
    out[row0 * 512 + bx * 64 + nh * 32 + lr] = acc00[r] + b0;
    out[row0 * 512 + bx * 64 + nh * 32 + 16 + lr] = acc01[r] + b1;
    out[row1 * 512 + bx * 64 + nh * 32 + lr] = acc10[r] + b0;
    out[row1 * 512 + bx * 64 + nh * 32 + 16 + lr] = acc11[r] + b1;
  }
}

// batched QKV GEMM, 128x64 tiles (grid 8 x 32 x 3 = 768 blocks, 3/CU)
__global__ __launch_bounds__(256) void gemm_qkv(const short* __restrict__ A,
                                                const short* __restrict__ Wq,
                                                const short* __restrict__ Wk,
                                                const short* __restrict__ Wv,
                                                const float* __restrict__ bv,
                                                float* __restrict__ Qo,
                                                float* __restrict__ Ko,
                                                short* __restrict__ Vt) {
  switch (blockIdx.z) {
    case 0: gemm_core128<0>(A, Wq, nullptr, Qo, blockIdx.x, blockIdx.y); break;
    case 1: gemm_core128<0>(A, Wk, nullptr, Ko, blockIdx.x, blockIdx.y); break;
    default: gemm_core128<1>(A, Wv, bv, Vt, blockIdx.x, blockIdx.y); break;
  }
}

// output GEMM stays 64x64 (512 blocks, 2/CU — avoids r11's 1-block/CU trap)
__global__ __launch_bounds__(256) void gemm_bf(const short* __restrict__ A,
                                               const short* __restrict__ W,
                                               const float* __restrict__ bias,
                                               float* __restrict__ out) {
  gemm_core64(A, W, bias, out, blockIdx.x, blockIdx.y);
}

// ---------------- hyperbolic epilogue v4: 2 rows/block, float4 (r13 verified) ----------------
__global__ __launch_bounds__(256) void hyp_epilogue_v4(const float* __restrict__ Qb,
                                                       const float* __restrict__ Kb,
                                                       const float* __restrict__ bbase,
                                                       short* __restrict__ Qbf,
                                                       short* __restrict__ Kbf,
                                                       float* __restrict__ q2h,
                                                       float* __restrict__ k2h) {
  const int which = blockIdx.y;
  const float* Y = which ? Kb : Qb;
  const float* bb = bbase + (size_t)which * 520;
  short* Ybf = which ? Kbf : Qbf;
  float* y2h = which ? k2h : q2h;
  const int t = threadIdx.x;
  const int half = t >> 7, tc = t & 127;
  const int row = blockIdx.x * 2 + half;

  float4 y = ((const float4*)(Y + (size_t)row * 512))[tc];
  float4 w = ((const float4*)bb)[tc];
  __shared__ float red[8];
  float sn = wave_sum64(y.x * y.x + y.y * y.y + y.z * y.z + y.w * y.w);
  float sd = wave_sum64(y.x * w.x + y.y * w.y + y.z * w.z + y.w * w.w);
  if ((t & 63) == 0) { red[t >> 6] = sn; red[4 + (t >> 6)] = sd; }
  __syncthreads();
  float n2 = red[half * 2] + red[half * 2 + 1];
  float dt = red[4 + half * 2] + red[4 + half * 2 + 1];
  float y2 = bb[512];
  float n = sqrtf(n2);
  float nm = fmaxf(n, EPSF);
  float tt = fminf(nm, 15.f);
  float f = tanhf(tt) / nm;
  float on = f * nm;
  if (on > CLAMPF) f *= CLAMPF / on;
  float x2 = f * f * n2;
  float xy = f * dt;
  float A = 1.f + 2.f * xy + y2;
  float Bc = 1.f - x2;
  float den = fmaxf(1.f + 2.f * xy + x2 * y2, EPSF);
  float num2 = A * A * x2 + Bc * Bc * y2 + 2.f * A * Bc * xy;
  float nn = sqrtf(fmaxf(num2, 0.f)) / den;
  float nnm = fmaxf(nn, EPSF);
  float s2 = (nnm > CLAMPF) ? (CLAMPF / nnm) : 1.f;
  float g = s2 / den;
  float ox = g * (A * f * y.x + Bc * w.x);
  float oy = g * (A * f * y.y + Bc * w.y);
  float oz = g * (A * f * y.z + Bc * w.z);
  float ow = g * (A * f * y.w + Bc * w.w);
  uint2 o;
  o.x = cvt_pk_bf16(ox, oy);
  o.y = cvt_pk_bf16(oz, ow);
  ((uint2*)(Ybf + (size_t)row * 512))[tc] = o;
  float hs = ox * ox + oy * oy + oz * oz + ow * ow;
  hs += __shfl_xor(hs, 1, 64);
  hs += __shfl_xor(hs, 2, 64);
  hs += __shfl_xor(hs, 4, 64);
  hs += __shfl_xor(hs, 8, 64);
  if ((tc & 15) == 0) y2h[(size_t)(tc >> 4) * 4096 + row] = hs;
}

// ---------------- MFMA flash attention v8 (r17 verified, unchanged) ----------------
__global__ __launch_bounds__(512, 2) void attn_mfma_v8(const short* __restrict__ Qbf,
                                                       const short* __restrict__ Kbf,
                                                       const float* __restrict__ q2h,
                                                       const float* __restrict__ k2h,
                                                       const short* __restrict__ Vt,
                                                       short* __restrict__ Obf) {
  __shared__ __align__(16) short Ks[64][72];
  __shared__ __align__(16) short Vs[64][72];
  __shared__ __align__(16) float k2s[64];
  __shared__ __align__(16) float Ls[4][16][68];
  __shared__ float lsb[4][16];

  const int t = threadIdx.x;
  const int id = blockIdx.x;               // id = qt*32 + b*8 + hd
  const int qt = id >> 5;                  // 0..15 (64-query tiles)
  const int pr = (((id >> 3) & 3) << 3) | (id & 7);
  const int hd = pr & 7, b = pr >> 3;
  const int wave = t >> 6, lane = t & 63, lg = lane >> 4, lr = lane & 15;
  const int qh = wave >> 1, kh = wave & 1;

  const size_t qrow = (size_t)(b * 1024 + qt * 64 + qh * 16 + lr);
  const bf16x8 qf0 = *(const bf16x8*)(Qbf + qrow * 512 + hd * 64 + lg * 8);
  const bf16x8 qf1 = *(const bf16x8*)(Qbf + qrow * 512 + hd * 64 + 32 + lg * 8);

  const float q2 = q2h[(size_t)hd * 4096 + b * 1024 + qt * 64 + qh * 16 + lr];
  const float bc = 1.f - q2;               // > 0 (norms clamped < 1)
  const float q2p1 = 1.f + q2;
  // log2(u0) with u0 = 5.000025e-6 (the n<=0.99999 clamp)
  const float Xmin = 0.125f * (-17.6096137f - __builtin_amdgcn_logf(bc));

  const int sr = t >> 3, q8 = t & 7;
  const int p32 = sr & 31;
  const int kwr = (sr & 32) | (((p32 >> 2) & 1) << 4) | (((p32 >> 3) & 3) << 2) | (p32 & 3);
  const short* kgp = Kbf + (size_t)(b * 1024 + sr) * 512 + hd * 64 + q8 * 8;
  const short* vgp = Vt + ((size_t)(b * 8 + hd) * 64 + sr) * 1024 + q8 * 8;
  const float* k2gp = k2h + (size_t)hd * 4096 + b * 1024 + t;

  int4 rk0 = *(const int4*)kgp;
  int4 rv0 = *(const int4*)vgp;
  float rk2 = (t < 64) ? (1.f - *k2gp) : 0.f;   // mk = 1 - k2

  f32x4 z = {0.f, 0.f, 0.f, 0.f};
  f32x4 acc0 = z, acc1 = z, acc2 = z, acc3 = z;
  float ls = 0.f;
  const int krow = kh * 32 + lr;
  const int kcol = kh * 32 + lg * 8;

  for (int kt = 0; kt < 16; ++kt) {
    __syncthreads();
    *(int4*)&Ks[kwr][q8 * 8] = rk0;
    *(int4*)&Vs[sr][q8 * 8] = rv0;
    if (t < 64) k2s[t] = rk2;
    __syncthreads();
    if (kt < 15) {
      kgp += 64 * 512; vgp += 64; k2gp += 64;
      rk0 = *(const int4*)kgp;
      rv0 = *(const int4*)vgp;
      if (t < 64) rk2 = 1.f - *k2gp;
    }

    bf16x8 kf0 = *(const bf16x8*)&Ks[krow][lg * 8];
    bf16x8 kf1 = *(const bf16x8*)&Ks[krow][32 + lg * 8];
    bf16x8 kg0 = *(const bf16x8*)&Ks[krow + 16][lg * 8];
    bf16x8 kg1 = *(const bf16x8*)&Ks[krow + 16][32 + lg * 8];
    __builtin_amdgcn_s_setprio(1);
    f32x4 sA = MFMA16(kf0, qf0, z);
    sA = MFMA16(kf1, qf1, sA);
    f32x4 sB = MFMA16(kg0, qf0, z);
    sB = MFMA16(kg1, qf1, sB);
    __builtin_amdgcn_s_setprio(0);

    float pA[4], pB[4];
#pragma unroll
    for (int r = 0; r < 4; ++r) {
      float d = sA[r];
      float mk = k2s[kh * 32 + lg * 8 + r];
      float den = fmaxf(fmaf(-2.f, d, fmaf(-q2, mk, q2p1)), EPSF);  // 1+q2*k2-2d
      float t1 = fmaxf(fmaf(-bc, mk, den), 0.f);                     // den - bc*mk
      float sq = __builtin_amdgcn_sqrtf(den * t1);                   // sqrt(num2)
      float vv = den + sq;
      float wv = mk * den;
      float X = fmaf(0.125f, __builtin_amdgcn_logf(wv),
                     -0.25f * __builtin_amdgcn_logf(vv));
      pA[r] = __builtin_amdgcn_exp2f(fmaxf(X, Xmin));
    }
#pragma unroll
    for (int r = 0; r < 4; ++r) {
      float d = sB[r];
      float mk = k2s[kh * 32 + lg * 8 + 4 + r];
      float den = fmaxf(fmaf(-2.f, d, fmaf(-q2, mk, q2p1)), EPSF);
      float t1 = fmaxf(fmaf(-bc, mk, den), 0.f);
      float sq = __builtin_amdgcn_sqrtf(den * t1);
      float vv = den + sq;
      float wv = mk * den;
      float X = fmaf(0.125f, __builtin_amdgcn_logf(wv),
                     -0.25f * __builtin_amdgcn_logf(vv));
      pB[r] = __builtin_amdgcn_exp2f(fmaxf(X, Xmin));
    }
    ls += (pA[0] + pA[1] + pA[2] + pA[3]) + (pB[0] + pB[1] + pB[2] + pB[3]);

    union { unsigned u[4]; bf16x8 v; } pf;
    pf.u[0] = cvt_pk_bf16(pA[0], pA[1]);
    pf.u[1] = cvt_pk_bf16(pA[2], pA[3]);
    pf.u[2] = cvt_pk_bf16(pB[0], pB[1]);
    pf.u[3] = cvt_pk_bf16(pB[2], pB[3]);

    bf16x8 v0 = *(const bf16x8*)&Vs[lr][kcol];
    bf16x8 v1 = *(const bf16x8*)&Vs[16 + lr][kcol];
    bf16x8 v2 = *(const bf16x8*)&Vs[32 + lr][kcol];
    bf16x8 v3 = *(const bf16x8*)&Vs[48 + lr][kcol];
    __builtin_amdgcn_s_setprio(1);
    acc0 = MFMA16(v0, pf.v, acc0);
    acc1 = MFMA16(v1, pf.v, acc1);
    acc2 = MFMA16(v2, pf.v, acc2);
    acc3 = MFMA16(v3, pf.v, acc3);
    __builtin_amdgcn_s_setprio(0);
  }

  ls += __shfl_xor(ls, 16, 64);
  ls += __shfl_xor(ls, 32, 64);

  if (kh == 1) {
    float* Lq = &Ls[qh][lr][0];
    *(f32x4*)(Lq + lg * 4) = acc0;
    *(f32x4*)(Lq + 16 + lg * 4) = acc1;
    *(f32x4*)(Lq + 32 + lg * 4) = acc2;
    *(f32x4*)(Lq + 48 + lg * 4) = acc3;
    if (lg == 0) lsb[qh][lr] = ls;
  }
  __syncthreads();
  if (kh == 0) {
    const float* Lq = &Ls[qh][lr][0];
    acc0 += *(const f32x4*)(Lq + lg * 4);
    acc1 += *(const f32x4*)(Lq + 16 + lg * 4);
    acc2 += *(const f32x4*)(Lq + 32 + lg * 4);
    acc3 += *(const f32x4*)(Lq + 48 + lg * 4);
    float inv = 1.f / (ls + lsb[qh][lr]);
    short* ob = Obf + qrow * 512 + hd * 64 + lg * 4;
    uint2 pk;
    pk.x = cvt_pk_bf16(acc0[0] * inv, acc0[1] * inv);
    pk.y = cvt_pk_bf16(acc0[2] * inv, acc0[3] * inv);
    *(uint2*)(ob) = pk;
    pk.x = cvt_pk_bf16(acc1[0] * inv, acc1[1] * inv);
    pk.y = cvt_pk_bf16(acc1[2] * inv, acc1[3] * inv);
    *(uint2*)(ob + 16) = pk;
    pk.x = cvt_pk_bf16(acc2[0] * inv, acc2[1] * inv);
    pk.y = cvt_pk_bf16(acc2[2] * inv, acc2[3] * inv);
    *(uint2*)(ob + 32) = pk;
    pk.x = cvt_pk_bf16(acc3[0] * inv, acc3[1] * inv);
    pk.y = cvt_pk_bf16(acc3[2] * inv, acc3[3] * inv);
    *(uint2*)(ob + 48) = pk;
  }
}

// ---------------- launch ----------------
extern "C" void kernel_launch(void* const* d_in, const int* in_sizes, int n_in,
                              void* d_out, int out_size, void* d_ws, size_t ws_size,
                              hipStream_t stream) {
  const float* x  = (const float*)d_in[0];
  const float* Wq = (const float*)d_in[1];
  const float* bq = (const float*)d_in[2];
  const float* Wk = (const float*)d_in[3];
  const float* bk = (const float*)d_in[4];
  const float* Wv = (const float*)d_in[5];
  const float* bv = (const float*)d_in[6];
  const float* Wo = (const float*)d_in[7];
  const float* bo = (const float*)d_in[8];
  float* out = (float*)d_out;
  float* ws  = (float*)d_ws;

  const size_t M1 = 1048576ull;  // 1M floats
  float* Qb    = ws;
  float* Kb    = ws + 2 * M1;
  short* Vt    = (short*)(ws + 4 * M1);
  short* xe_bf = (short*)(ws + 5 * M1);
  short* Qbf   = (short*)(ws + 5 * M1);      // reuse xe after gemm_qkv
  short* Wqbf  = (short*)(ws + 6 * M1);
  short* Wkbf  = (short*)(ws + 6 * M1 + 131072);
  short* Wvbf  = (short*)(ws + 6 * M1 + 262144);
  short* Wobf  = (short*)(ws + 6 * M1 + 393216);
  short* attn_out = (short*)(ws + 6 * M1 + 524288);
  short* Kbf = (short*)out;
  float* bb  = out + M1;
  float* q2h = out + M1 + 2048;
  float* k2h = out + M1 + 2048 + 32768;

  hipLaunchKernelGGL(prep_logmap, dim3(2562), dim3(256), 0, stream,
                     x, Wq, Wk, Wv, Wo, bq, bk, xe_bf, Wqbf, Wkbf, Wvbf, Wobf, bb);

  hipLaunchKernelGGL(gemm_qkv, dim3(8, 32, 3), dim3(256), 0, stream,
                     xe_bf, Wqbf, Wkbf, Wvbf, bv, Qb, Kb, Vt);

  hipLaunchKernelGGL(hyp_epilogue_v4, dim3(2048, 2), dim3(256), 0, stream,
                     Qb, Kb, bb, Qbf, Kbf, q2h, k2h);

  hipLaunchKernelGGL(attn_mfma_v8, dim3(512), dim3(512), 0, stream,
                     Qbf, Kbf, q2h, k2h, Vt, attn_out);

  hipLaunchKernelGGL(gemm_bf, dim3(8, 64), dim3(256), 0, stream, attn_out, Wobf, bo, out);
}